// Round 4
// baseline (859.019 us; speedup 1.0000x reference)
//
#include <hip/hip_runtime.h>
#include <hip/hip_fp16.h>
#include <cstddef>
#include <cstdint>

#define NN 50000
#define DEG 8
#define EE (NN*DEG)
#define RT_CNT 3125   // NN/16 row-tiles
#define KSTEPS 36     // K=1152 / 32:  [xt(4) | (rel,tw) x {Bm,mn,mx,std}(32)]
#define SPAD 132      // stats LDS row pad

typedef __attribute__((ext_vector_type(8))) short short8;
typedef __attribute__((ext_vector_type(4))) float f32x4;

union Pack8 { __half h[8]; uint4 u; };

// ---------------------------------------------------------------------------
// K0: build neighbor lists (constant degree 8) via atomic counters
// ---------------------------------------------------------------------------
__global__ void k_build_nbr(const int* __restrict__ ef, int* __restrict__ cnt,
                            int* __restrict__ fwd_nbr, int* __restrict__ rev_nbr) {
    int e = blockIdx.x * blockDim.x + threadIdx.x;
    if (e >= EE) return;
    int s = ef[e], d = ef[EE + e];
    int p = atomicAdd(&cnt[d], 1);
    fwd_nbr[d * DEG + p] = s;
    int q = atomicAdd(&cnt[NN + s], 1);
    rev_nbr[s * DEG + q] = d;
}

// ---------------------------------------------------------------------------
// K0b: fold post_W [16][416][32] -> Pfold [16][160][32]
// (deg==8 -> degree scalers are exactly 1; three agg copies sum)
// Pfold rows: [xt(0:32) | mean(32:64) | mn(64:96) | mx(96:128) | std(128:160)]
// ---------------------------------------------------------------------------
__global__ void k_fold_post(const float* __restrict__ post_W, float* __restrict__ Pfold) {
    int idx = blockIdx.x * blockDim.x + threadIdx.x;
    const int total = 16 * 160 * 32;
    if (idx >= total) return;
    int g = idx & 31;
    int row = (idx >> 5) % 160;
    int m = idx / (160 * 32);
    const float* W = post_W + (size_t)m * 416 * 32;
    float v;
    if (row < 32) v = W[row * 32 + g];
    else {
        int r = row - 32;
        v = W[(32 + r) * 32 + g] + W[(160 + r) * 32 + g] + W[(288 + r) * 32 + g];
    }
    Pfold[idx] = v;
}

// ---------------------------------------------------------------------------
// K0c: per (l,r,tw) m4-block: Q_xt[32][32] = P_xt + Wt @ Psum3, and
// t3[32] = post_b + preb @ Psum3, where Psum3 = P_mean+P_mn+P_mx.
// (bse = xt@Wt + preb is folded out of mean/mn/mx rows.)
// ---------------------------------------------------------------------------
__global__ __launch_bounds__(256) void k_prep(
    const float* __restrict__ Pfold, const float* __restrict__ pre_W,
    const float* __restrict__ pre_b, const float* __restrict__ post_b,
    float* __restrict__ Qbuf, float* __restrict__ T3buf) {
    __shared__ float Ps[32 * 32];
    int m4 = blockIdx.x;             // (l*2+r)*4+tw
    int m2 = m4 >> 2, tw = m4 & 3;
    int tid = threadIdx.x;
    const float* Pf = Pfold + (size_t)m4 * 160 * 32;
    for (int i = tid; i < 1024; i += 256)
        Ps[i] = Pf[32 * 32 + i] + Pf[64 * 32 + i] + Pf[96 * 32 + i];
    __syncthreads();
    for (int i = tid; i < 1024; i += 256) {
        int f = i >> 5, j = i & 31;
        float v = Pf[f * 32 + j];
        const float* Wt = &pre_W[(size_t)(m4 * 64 + f) * 32];
#pragma unroll
        for (int g = 0; g < 32; g++) v += Wt[g] * Ps[g * 32 + j];
        Qbuf[(size_t)m4 * 1024 + i] = v;
    }
    if (tid < 32) {
        int j = tid;
        float v = post_b[m2 * 128 + tw * 32 + j];
#pragma unroll
        for (int g = 0; g < 32; g++)
            v += pre_b[m2 * 128 + tw * 32 + g] * Ps[g * 32 + j];
        T3buf[m4 * 32 + j] = v;
    }
}

// ---------------------------------------------------------------------------
// K0d: build combined weight Wc[l][k=1152][n=128] packed in MFMA B-frag f16
// layout Wcp[((l*8+t)*KSTEPS+ks)*64+lane][e], k=ks*32+(lane>>4)*8+e,
// n=t*16+(lane&15); plus combined bias bc[l][128].
// k<128 (xt): sum over rel of Q_xt @ lin_W ; k>=128: stat rows @ lin_W.
// ---------------------------------------------------------------------------
__global__ void k_make_wc(const float* __restrict__ Pfold, const float* __restrict__ lin_W,
                          const float* __restrict__ lin_b, const float* __restrict__ Qbuf,
                          const float* __restrict__ T3buf,
                          __half* __restrict__ Wcp, float* __restrict__ bc) {
    int gid = blockIdx.x * blockDim.x + threadIdx.x;
    const int NW = 2 * 8 * KSTEPS * 64;
    if (gid < NW) {
        int lane = gid & 63;
        int ks = (gid >> 6) % KSTEPS;
        int t = (gid / (64 * KSTEPS)) & 7;
        int l = gid / (64 * KSTEPS * 8);
        int quad = lane >> 4, nl = lane & 15;
        int n = t * 16 + nl;
        Pack8 pk;
#pragma unroll
        for (int e = 0; e < 8; e++) {
            int k = ks * 32 + quad * 8 + e;
            float v = 0.f;
            if (k < 128) {
                int tw = k >> 5, f = k & 31;
                for (int r = 0; r < 2; r++) {
                    const float* Q = &Qbuf[(size_t)(((l * 2 + r) * 4 + tw)) * 1024 + f * 32];
                    const float* Wl = &lin_W[((size_t)(l * 2 + r) * 128 + tw * 32) * 128 + n];
#pragma unroll
                    for (int j = 0; j < 32; j++) v += Q[j] * Wl[(size_t)j * 128];
                }
            } else {
                int kk = k - 128;
                int r = kk >> 9, tw = (kk >> 7) & 3, s = (kk >> 5) & 3, f = kk & 31;
                const float* P = &Pfold[(size_t)(((l * 2 + r) * 4 + tw)) * 160 * 32 +
                                        ((s + 1) * 32 + f) * 32];
                const float* Wl = &lin_W[((size_t)(l * 2 + r) * 128 + tw * 32) * 128 + n];
#pragma unroll
                for (int j = 0; j < 32; j++) v += P[j] * Wl[(size_t)j * 128];
            }
            pk.h[e] = __float2half(v);
        }
        *(uint4*)&Wcp[(size_t)gid * 8] = pk.u;
    }
    int b2 = gid - NW;
    if (b2 >= 0 && b2 < 256) {
        int l = b2 >> 7, n = b2 & 127;
        float v = lin_b[(l * 2 + 0) * 128 + n] + lin_b[(l * 2 + 1) * 128 + n];
        for (int r = 0; r < 2; r++)
            for (int tw = 0; tw < 4; tw++) {
                const float* t3 = &T3buf[(((l * 2 + r) * 4 + tw)) * 32];
                const float* Wl = &lin_W[((size_t)(l * 2 + r) * 128 + tw * 32) * 128 + n];
                for (int j = 0; j < 32; j++) v += t3[j] * Wl[(size_t)j * 128];
            }
        bc[b2] = v;
    }
}

// ---------------------------------------------------------------------------
// K1: [nrows,128] @ [128,128] + bias (+relu) -> Y   (fp32 VALU, input layer)
// ---------------------------------------------------------------------------
template<int RELU>
__global__ __launch_bounds__(256) void k_gemm128(
    const float* __restrict__ X, const float* __restrict__ W,
    const float* __restrict__ b, float* __restrict__ Y, int nrows) {
    __shared__ float Ws[64 * 128];
    __shared__ float Xs[32 * 128];
    int tid = threadIdx.x;
    int row0 = blockIdx.x * 32;
    for (int i = tid; i < 32 * 128; i += 256) {
        int r = row0 + (i >> 7);
        Xs[i] = (r < nrows) ? X[(size_t)r * 128 + (i & 127)] : 0.f;
    }
    int col = tid & 127, rb = tid >> 7;
    float acc[16];
#pragma unroll
    for (int i = 0; i < 16; i++) acc[i] = 0.f;
    for (int kc = 0; kc < 2; kc++) {
        __syncthreads();
        for (int i = tid; i < 64 * 128; i += 256) Ws[i] = W[kc * 64 * 128 + i];
        __syncthreads();
        for (int k = 0; k < 64; k++) {
            float w = Ws[k * 128 + col];
#pragma unroll
            for (int i = 0; i < 16; i++)
                acc[i] += Xs[(rb + 2 * i) * 128 + kc * 64 + k] * w;
        }
    }
    float bias = b[col];
#pragma unroll
    for (int i = 0; i < 16; i++) {
        int r = row0 + rb + 2 * i;
        if (r < nrows) {
            float v = acc[i] + bias;
            if (RELU) v = fmaxf(v, 0.f);
            Y[(size_t)r * 128 + col] = v;
        }
    }
}

// ---------------------------------------------------------------------------
// K2: B planes (src-side pre-projection), f16 output
// ---------------------------------------------------------------------------
__global__ __launch_bounds__(256) void k_preB(
    const float* __restrict__ hbuf, const float* __restrict__ pre_W,
    int layer, __half* __restrict__ Bplanes) {
    __shared__ float Wb[2 * 4 * 32 * 32];  // 32 KB
    __shared__ float Xs[16 * 128];         // 8 KB
    int tid = threadIdx.x;
    for (int i = tid; i < 8192; i += 256) {
        int g = i & 31, f = (i >> 5) & 31, t = (i >> 10) & 3, r = i >> 12;
        Wb[i] = pre_W[((((layer * 2 + r) * 4 + t) * 64) + 32 + f) * 32 + g];
    }
    int r = tid >> 7, c = tid & 127, t = c >> 5, g = c & 31;
    const float* wp = &Wb[((r * 4 + t) * 32) * 32 + g];
    for (int base = blockIdx.x * 16; base < NN; base += gridDim.x * 16) {
        __syncthreads();
        for (int i = tid; i < 16 * 128; i += 256) {
            int n = base + (i >> 7);
            Xs[i] = (n < NN) ? hbuf[(size_t)n * 128 + (i & 127)] : 0.f;
        }
        __syncthreads();
        for (int n = 0; n < 16; n++) {
            if (base + n >= NN) break;
            float acc = 0.f;
#pragma unroll
            for (int f = 0; f < 32; f++) acc += Xs[n * 128 + t * 32 + f] * wp[f * 32];
            Bplanes[(size_t)r * NN * 128 + (size_t)(base + n) * 128 + c] = __float2half(acc);
        }
    }
}

// ---------------------------------------------------------------------------
// K3: pure gather + B-stats, MFMA-A-packed f16 output (dst-side projection
// folded into Wc). 512 thr = 16 node-slots x 32 g; blockIdx.y = rel*4+tw.
// Writes stat ksteps 4+(rel*4+tw)*4 .. +3; rel0 blocks also pack xt kstep=tw
// straight from hbuf. Layer-independent (no weights needed).
// ---------------------------------------------------------------------------
__global__ __launch_bounds__(512) void k_agg_stats(
    const float* __restrict__ hbuf, const __half* __restrict__ Bplanes,
    const int* __restrict__ fwd_nbr, const int* __restrict__ rev_nbr,
    __half* __restrict__ Ap) {
    __shared__ float S[16 * SPAD];
    int tid = threadIdx.x;
    int rel = blockIdx.y >> 2, tw = blockIdx.y & 3;
    const int* nbr = rel ? rev_nbr : fwd_nbr;
    const __half* Bp = Bplanes + (size_t)rel * NN * 128;
    int slot = tid >> 5, g = tid & 31;
    int c = tw * 32 + g;
    int ksS = 4 + (rel * 4 + tw) * 4;
    int packN = rel ? 256 : 320;
    int kl = tid >> 6, lane = tid & 63, mm = lane & 15, quad = lane >> 4;
    for (int rt = blockIdx.x; rt < RT_CNT; rt += gridDim.x) {
        int d = rt * 16 + slot;
        const int4* nb4 = (const int4*)&nbr[d * 8];
        int4 na = nb4[0], nb = nb4[1];
        int idx[8] = {na.x, na.y, na.z, na.w, nb.x, nb.y, nb.z, nb.w};
        float s = 0.f, s2 = 0.f, mn = 1e30f, mx = -1e30f;
#pragma unroll
        for (int k = 0; k < 8; k++) {
            float bv = __half2float(Bp[(size_t)idx[k] * 128 + c]);
            s += bv; s2 += bv * bv; mn = fminf(mn, bv); mx = fmaxf(mx, bv);
        }
        float Bm = s * 0.125f;
        float stdv = sqrtf(fmaxf(s2 * 0.125f - Bm * Bm, 0.f) + 1e-5f);
        float* Sr = &S[slot * SPAD];
        Sr[g] = Bm;
        Sr[32 + g] = mn;
        Sr[64 + g] = mx;
        Sr[96 + g] = stdv;
        __syncthreads();
        if (tid < packN) {
            Pack8 pk;
            int ksD;
            float4 v0, v1;
            if (kl < 4) {
                const float* Sp = &S[mm * SPAD + kl * 32 + quad * 8];
                v0 = *(const float4*)Sp; v1 = *(const float4*)(Sp + 4);
                ksD = ksS + kl;
            } else {  // xt straight from hbuf (rel0 only)
                const float* Hp = &hbuf[(size_t)(rt * 16 + mm) * 128 + tw * 32 + quad * 8];
                v0 = *(const float4*)Hp; v1 = *(const float4*)(Hp + 4);
                ksD = tw;
            }
            pk.h[0] = __float2half(v0.x); pk.h[1] = __float2half(v0.y);
            pk.h[2] = __float2half(v0.z); pk.h[3] = __float2half(v0.w);
            pk.h[4] = __float2half(v1.x); pk.h[5] = __float2half(v1.y);
            pk.h[6] = __float2half(v1.z); pk.h[7] = __float2half(v1.w);
            *(uint4*)&Ap[(((size_t)rt * KSTEPS + ksD) * 64 + lane) * 8] = pk.u;
        }
        __syncthreads();
    }
}

// ---------------------------------------------------------------------------
// K4: MFMA GEMM  stats[N,1152] @ Wc[1152,128] + bc -> ybuf, fused BN sums.
// Software-pipelined: all 9 loads (1 A + 8 B) for step ks+1 issued before the
// MFMA burst of step ks (double-buffered regs) -> deep MLP, HBM-saturating.
// ---------------------------------------------------------------------------
__global__ __launch_bounds__(256) void k_gemm_mfma(
    const __half* __restrict__ Ap, const __half* __restrict__ Wcp,
    const float* __restrict__ bc, float* __restrict__ Y,
    float* __restrict__ bnsum, float* __restrict__ bnsum2) {
    __shared__ float bnred[256];
    int tid = threadIdx.x;
    bnred[tid] = 0.f;
    __syncthreads();
    int wave = tid >> 6, lane = tid & 63;
    int rt = blockIdx.x * 4 + wave;
    bool active = rt < RT_CNT;
    f32x4 acc[8];
#pragma unroll
    for (int t = 0; t < 8; t++) acc[t] = (f32x4){0.f, 0.f, 0.f, 0.f};
    if (active) {
        const short8* Ab = (const short8*)Ap + (size_t)rt * KSTEPS * 64 + lane;
        const short8* Bb = (const short8*)Wcp + lane;
        short8 aC = Ab[0];
        short8 bC[8];
#pragma unroll
        for (int t = 0; t < 8; t++) bC[t] = Bb[(size_t)t * KSTEPS * 64];
#pragma unroll 2
        for (int ks = 0; ks < KSTEPS; ks++) {
            int nxt = (ks + 1 < KSTEPS) ? ks + 1 : 0;
            short8 aN = Ab[(size_t)nxt * 64];
            short8 bN[8];
#pragma unroll
            for (int t = 0; t < 8; t++) bN[t] = Bb[((size_t)t * KSTEPS + nxt) * 64];
#pragma unroll
            for (int t = 0; t < 8; t++)
                acc[t] = __builtin_amdgcn_mfma_f32_16x16x32_f16(aC, bC[t], acc[t], 0, 0, 0);
            aC = aN;
#pragma unroll
            for (int t = 0; t < 8; t++) bC[t] = bN[t];
        }
        int nl = lane & 15, quad = lane >> 4;
#pragma unroll
        for (int t = 0; t < 8; t++) {
            int n = t * 16 + nl;
            float bias = bc[n];
            float ls = 0.f, ls2 = 0.f;
#pragma unroll
            for (int r = 0; r < 4; r++) {
                float v = acc[t][r] + bias;
                int node = rt * 16 + quad * 4 + r;
                Y[(size_t)node * 128 + n] = v;
                ls += v; ls2 += v * v;
            }
            ls += __shfl_xor(ls, 16); ls += __shfl_xor(ls, 32);
            ls2 += __shfl_xor(ls2, 16); ls2 += __shfl_xor(ls2, 32);
            if (quad == 0) { atomicAdd(&bnred[n], ls); atomicAdd(&bnred[128 + n], ls2); }
        }
    }
    __syncthreads();
    if (tid < 128) {
        atomicAdd(&bnsum[tid], bnred[tid]);
        atomicAdd(&bnsum2[tid], bnred[128 + tid]);
    }
}

// ---------------------------------------------------------------------------
// K5: BN finalize
// ---------------------------------------------------------------------------
__global__ void k_bn_final(const float* __restrict__ bnsum, const float* __restrict__ bnsum2,
                           const float* __restrict__ gamma, const float* __restrict__ beta,
                           int layer, float* __restrict__ scale, float* __restrict__ shift) {
    int c = threadIdx.x;
    float mu = bnsum[c] * (1.f / NN);
    float var = bnsum2[c] * (1.f / NN) - mu * mu;
    float sc = gamma[layer * 128 + c] * rsqrtf(var + 1e-5f);
    scale[c] = sc;
    shift[c] = beta[layer * 128 + c] - mu * sc;
}

// ---------------------------------------------------------------------------
// K6: apply BN + relu (float4)
// ---------------------------------------------------------------------------
__global__ void k_bn_apply(const float4* __restrict__ y, const float* __restrict__ scale,
                           const float* __restrict__ shift, float4* __restrict__ hout) {
    int i = blockIdx.x * blockDim.x + threadIdx.x;
    if (i >= NN * 32) return;
    int cb = (i & 31) * 4;
    float4 v = y[i];
    v.x = fmaxf(scale[cb + 0] * v.x + shift[cb + 0], 0.f);
    v.y = fmaxf(scale[cb + 1] * v.y + shift[cb + 1], 0.f);
    v.z = fmaxf(scale[cb + 2] * v.z + shift[cb + 2], 0.f);
    v.w = fmaxf(scale[cb + 3] * v.w + shift[cb + 3], 0.f);
    hout[i] = v;
}

// ---------------------------------------------------------------------------
// K7: fused MLP: out = relu(h @ W1 + b1) @ W2 + b2, intermediate in LDS
// ---------------------------------------------------------------------------
__global__ __launch_bounds__(256) void k_mlp(
    const float* __restrict__ X, const float* __restrict__ W1,
    const float* __restrict__ b1, const float* __restrict__ W2,
    const float* __restrict__ b2, float* __restrict__ out, int nrows) {
    __shared__ float Ws[64 * 128];  // 32 KB (reused for W2)
    __shared__ float Xs[32 * 128];  // 16 KB
    __shared__ float T1[32 * 128];  // 16 KB
    int tid = threadIdx.x;
    int row0 = blockIdx.x * 32;
    for (int i = tid; i < 32 * 128; i += 256) {
        int r = row0 + (i >> 7);
        Xs[i] = (r < nrows) ? X[(size_t)r * 128 + (i & 127)] : 0.f;
    }
    int col = tid & 127, rb = tid >> 7;
    float acc[16];
#pragma unroll
    for (int i = 0; i < 16; i++) acc[i] = 0.f;
    for (int kc = 0; kc < 2; kc++) {
        __syncthreads();
        for (int i = tid; i < 64 * 128; i += 256) Ws[i] = W1[kc * 64 * 128 + i];
        __syncthreads();
        for (int k = 0; k < 64; k++) {
            float w = Ws[k * 128 + col];
#pragma unroll
            for (int i = 0; i < 16; i++)
                acc[i] += Xs[(rb + 2 * i) * 128 + kc * 64 + k] * w;
        }
    }
    float bias = b1[col];
#pragma unroll
    for (int i = 0; i < 16; i++)
        T1[(rb + 2 * i) * 128 + col] = fmaxf(acc[i] + bias, 0.f);
    __syncthreads();  // T1 complete; Ws free
    for (int i = tid; i < 128 * 32; i += 256) Ws[i] = W2[i];
    __syncthreads();
    int col2 = tid & 31, rb2 = tid >> 5;
    float acc2[4];
    float bias2 = b2[col2];
#pragma unroll
    for (int i = 0; i < 4; i++) acc2[i] = bias2;
    for (int k = 0; k < 128; k++) {
        float w = Ws[k * 32 + col2];
#pragma unroll
        for (int i = 0; i < 4; i++) acc2[i] += T1[(rb2 + 8 * i) * 128 + k] * w;
    }
#pragma unroll
    for (int i = 0; i < 4; i++) {
        int r = row0 + rb2 + 8 * i;
        if (r < nrows) out[(size_t)r * 32 + col2] = acc2[i];
    }
}

// ---------------------------------------------------------------------------
extern "C" void kernel_launch(void* const* d_in, const int* in_sizes, int n_in,
                              void* d_out, int out_size, void* d_ws, size_t ws_size,
                              hipStream_t stream) {
    const float* x      = (const float*)d_in[0];
    const float* W_in   = (const float*)d_in[1];
    const float* b_in   = (const float*)d_in[2];
    const float* pre_W  = (const float*)d_in[3];
    const float* pre_b  = (const float*)d_in[4];
    const float* post_W = (const float*)d_in[5];
    const float* post_b = (const float*)d_in[6];
    const float* lin_W  = (const float*)d_in[7];
    const float* lin_b  = (const float*)d_in[8];
    const float* bn_g   = (const float*)d_in[9];
    const float* bn_b   = (const float*)d_in[10];
    const float* mlp_W1 = (const float*)d_in[11];
    const float* mlp_b1 = (const float*)d_in[12];
    const float* mlp_W2 = (const float*)d_in[13];
    const float* mlp_b2 = (const float*)d_in[14];
    const int*   edge   = (const int*)d_in[15];
    float* out = (float*)d_out;

    char* w = (char*)d_ws;
    const size_t plane = (size_t)NN * 128 * sizeof(float);       // 25.6 MB
    float* hbuf = (float*)w; w += plane;
    float* ybuf = (float*)w; w += plane;
    __half* Bpl = (__half*)w; w += plane;                        // both rels, f16
    __half* Ap  = (__half*)w; w += (size_t)NN * (KSTEPS * 32) * sizeof(__half);  // 115 MB
    int* fwd_nbr = (int*)w; w += (size_t)NN * DEG * sizeof(int);
    int* rev_nbr = (int*)w; w += (size_t)NN * DEG * sizeof(int);
    int* cnt     = (int*)w; w += (size_t)2 * NN * sizeof(int);
    float* Pfold = (float*)w; w += (size_t)16 * 160 * 32 * sizeof(float);
    float* Qbuf  = (float*)w; w += (size_t)16 * 1024 * sizeof(float);
    float* T3buf = (float*)w; w += (size_t)16 * 32 * sizeof(float);
    __half* Wcp  = (__half*)w; w += (size_t)2 * KSTEPS * 32 * 128 * sizeof(__half);
    float* bc    = (float*)w; w += 2 * 128 * sizeof(float);
    float* bnsum  = (float*)w; w += 128 * sizeof(float);
    float* bnsum2 = (float*)w; w += 128 * sizeof(float);
    float* scale  = (float*)w; w += 128 * sizeof(float);
    float* shift  = (float*)w; w += 128 * sizeof(float);

    const int gRows = (NN + 31) / 32;  // 1563

    hipMemsetAsync(cnt, 0, (size_t)2 * NN * sizeof(int), stream);
    k_build_nbr<<<(EE + 255) / 256, 256, 0, stream>>>(edge, cnt, fwd_nbr, rev_nbr);
    k_fold_post<<<(16 * 160 * 32 + 255) / 256, 256, 0, stream>>>(post_W, Pfold);
    k_prep<<<16, 256, 0, stream>>>(Pfold, pre_W, pre_b, post_b, Qbuf, T3buf);
    k_make_wc<<<(2 * 8 * KSTEPS * 64 + 256 + 255) / 256, 256, 0, stream>>>(
        Pfold, lin_W, lin_b, Qbuf, T3buf, Wcp, bc);

    // h = relu(x @ W_in + b_in)
    k_gemm128<1><<<gRows, 256, 0, stream>>>(x, W_in, b_in, hbuf, NN);

    for (int l = 0; l < 2; l++) {
        k_preB<<<256, 256, 0, stream>>>(hbuf, pre_W, l, Bpl);
        dim3 gag(391, 8);  // y = rel*4 + tower
        k_agg_stats<<<gag, 512, 0, stream>>>(hbuf, Bpl, fwd_nbr, rev_nbr, Ap);
        hipMemsetAsync(bnsum, 0, 2 * 128 * sizeof(float), stream);
        k_gemm_mfma<<<(RT_CNT + 3) / 4, 256, 0, stream>>>(
            Ap, Wcp + (size_t)l * KSTEPS * 32 * 128, bc + l * 128, ybuf, bnsum, bnsum2);
        k_bn_final<<<1, 128, 0, stream>>>(bnsum, bnsum2, bn_g, bn_b, l, scale, shift);
        k_bn_apply<<<(NN * 32 + 255) / 256, 256, 0, stream>>>(
            (const float4*)ybuf, scale, shift, (float4*)hbuf);
    }

    // out = relu(h @ mlp_W1 + b1) @ mlp_W2 + b2   (fused)
    k_mlp<<<gRows, 256, 0, stream>>>(hbuf, mlp_W1, mlp_b1, mlp_W2, mlp_b2, out, NN);
}

// Round 5
// 674.426 us; speedup vs baseline: 1.2737x; 1.2737x over previous
//
#include <hip/hip_runtime.h>
#include <hip/hip_fp16.h>
#include <cstddef>
#include <cstdint>

#define NN 50000
#define DEG 8
#define EE (NN*DEG)
#define RT_CNT 3125   // NN/16 row-tiles
#define KSTEPS 36     // K=1152 / 32:  [xt(4) | (rel,tw) x {Bm,mn,mx,std}(32)]
#define SPAD 132      // stats LDS row pad
#define W8L 18432     // Wcp layer stride in short8 units (KSTEPS*32*128/8)

typedef __attribute__((ext_vector_type(8))) short short8;
typedef __attribute__((ext_vector_type(4))) float f32x4;

union Pack8 { __half h[8]; uint4 u; };

// ---------------------------------------------------------------------------
// K0: build neighbor lists (constant degree 8) via atomic counters
// ---------------------------------------------------------------------------
__global__ void k_build_nbr(const int* __restrict__ ef, int* __restrict__ cnt,
                            int* __restrict__ fwd_nbr, int* __restrict__ rev_nbr) {
    int e = blockIdx.x * blockDim.x + threadIdx.x;
    if (e >= EE) return;
    int s = ef[e], d = ef[EE + e];
    int p = atomicAdd(&cnt[d], 1);
    fwd_nbr[d * DEG + p] = s;
    int q = atomicAdd(&cnt[NN + s], 1);
    rev_nbr[s * DEG + q] = d;
}

// ---------------------------------------------------------------------------
// K0w: full weight prep, one block per m4=(l,r,tw).
//  Pfold rows [xt|mean|mn|mx|std] folded in LDS (deg==8 -> scalers = 1,
//  three agg copies sum). Psum3 = P_mean+P_mn+P_mx; Q = P_xt + Wt@Psum3
//  (dst-side pre-projection folded out of mean/mn/mx); T3 = post_b+pre_b@Psum3.
//  Stat rows -> packed f16 MFMA-B layout directly (r-exclusive ksteps).
//  xt rows (summed over r) -> fp32 atomic staging Qw; bias -> atomic bc.
// ---------------------------------------------------------------------------
__global__ __launch_bounds__(256) void k_wprep(
    const float* __restrict__ post_W, const float* __restrict__ pre_W,
    const float* __restrict__ pre_b, const float* __restrict__ post_b,
    const float* __restrict__ lin_W, const float* __restrict__ lin_b,
    __half* __restrict__ Wcp, float* __restrict__ Qw, float* __restrict__ bc) {
    __shared__ float Pf[160 * 33];   // 21.1 KB (pad 33: bank-conflict-free dots)
    __shared__ float Wl[32 * 128];   // 16 KB lin_W tile
    __shared__ float Wt[32 * 32];    // 4 KB pre_W top
    __shared__ float Ps[32 * 32];    // 4 KB
    __shared__ float Q[32 * 32];     // 4 KB
    __shared__ float T3s[32];
    int tid = threadIdx.x;
    int m4 = blockIdx.x;             // ((l*2+r)*4+tw)
    int l = m4 >> 3, r = (m4 >> 2) & 1, tw = m4 & 3;
    const float* PW = post_W + (size_t)m4 * 416 * 32;
    // stage 1: fold Pf; load Wt, Wl
    for (int i = tid; i < 160 * 32; i += 256) {
        int row = i >> 5, g = i & 31;
        float v;
        if (row < 32) v = PW[row * 32 + g];
        else {
            int rr = row - 32;
            v = PW[(32 + rr) * 32 + g] + PW[(160 + rr) * 32 + g] + PW[(288 + rr) * 32 + g];
        }
        Pf[row * 33 + g] = v;
    }
    for (int i = tid; i < 1024; i += 256) Wt[i] = pre_W[(size_t)m4 * 2048 + i];
    for (int i = tid; i < 4096; i += 256)
        Wl[i] = lin_W[(size_t)(l * 2 + r) * 16384 + tw * 32 * 128 + i];
    __syncthreads();
    // stage 2: Psum3
    for (int i = tid; i < 1024; i += 256) {
        int g = i >> 5, j = i & 31;
        Ps[i] = Pf[(32 + g) * 33 + j] + Pf[(64 + g) * 33 + j] + Pf[(96 + g) * 33 + j];
    }
    __syncthreads();
    // stage 3: Q, T3
    for (int i = tid; i < 1024; i += 256) {
        int f = i >> 5, j = i & 31;
        float acc = Pf[f * 33 + j];
#pragma unroll
        for (int g = 0; g < 32; g++) acc += Wt[f * 32 + g] * Ps[g * 32 + j];
        Q[i] = acc;
    }
    if (tid < 32) {
        int j = tid;
        float v = post_b[m4 * 32 + j];
#pragma unroll
        for (int g = 0; g < 32; g++) v += pre_b[m4 * 32 + g] * Ps[g * 32 + j];
        T3s[j] = v;
    }
    __syncthreads();
    // stage 4a: stat rows, packed f16 B-frag layout
    for (int u = tid; u < 2048; u += 256) {
        int lane = u & 63, t = (u >> 6) & 7, s = u >> 9;
        int quad = lane >> 4, nl = lane & 15;
        int n = t * 16 + nl;
        Pack8 pk;
#pragma unroll
        for (int e = 0; e < 8; e++) {
            int f = quad * 8 + e;
            const float* Pr = &Pf[((s + 1) * 32 + f) * 33];
            float acc = 0.f;
#pragma unroll
            for (int j = 0; j < 32; j++) acc += Pr[j] * Wl[j * 128 + n];
            pk.h[e] = __float2half(acc);
        }
        int ks = 4 + r * 16 + tw * 4 + s;
        *(uint4*)&Wcp[((size_t)l * W8L + (t * KSTEPS + ks) * 64 + lane) * 8] = pk.u;
    }
    // stage 4b: xt partial -> Qw (atomic over r)
    for (int i = tid; i < 4096; i += 256) {
        int f = i >> 7, n = i & 127;
        float acc = 0.f;
#pragma unroll
        for (int j = 0; j < 32; j++) acc += Q[f * 32 + j] * Wl[j * 128 + n];
        atomicAdd(&Qw[(size_t)l * 16384 + (tw * 32 + f) * 128 + n], acc);
    }
    // stage 4c: bias
    if (tid < 128) {
        float v = 0.f;
#pragma unroll
        for (int j = 0; j < 32; j++) v += T3s[j] * Wl[j * 128 + tid];
        atomicAdd(&bc[l * 128 + tid], v);
        if ((m4 & 7) == 0)
            atomicAdd(&bc[l * 128 + tid],
                      lin_b[(2 * l) * 128 + tid] + lin_b[(2 * l + 1) * 128 + tid]);
    }
}

// ---------------------------------------------------------------------------
// K0x: pack xt rows (Qw fp32) into Wcp f16 B-frag layout (ks = tw in [0,4))
// ---------------------------------------------------------------------------
__global__ void k_pack_xt(const float* __restrict__ Qw, __half* __restrict__ Wcp) {
    int gid = blockIdx.x * blockDim.x + threadIdx.x;
    if (gid >= 2 * 4 * 8 * 64) return;
    int lane = gid & 63, t = (gid >> 6) & 7, ks = (gid >> 9) & 3, l = gid >> 11;
    int quad = lane >> 4;
    int n = t * 16 + (lane & 15);
    Pack8 pk;
#pragma unroll
    for (int e = 0; e < 8; e++)
        pk.h[e] = __float2half(Qw[(size_t)l * 16384 + (ks * 32 + quad * 8 + e) * 128 + n]);
    *(uint4*)&Wcp[((size_t)l * W8L + (t * KSTEPS + ks) * 64 + lane) * 8] = pk.u;
}

// ---------------------------------------------------------------------------
// K1: [nrows,128] @ [128,128] + bias (+relu) -> Y   (fp32 VALU, input layer)
// ---------------------------------------------------------------------------
template<int RELU>
__global__ __launch_bounds__(256) void k_gemm128(
    const float* __restrict__ X, const float* __restrict__ W,
    const float* __restrict__ b, float* __restrict__ Y, int nrows) {
    __shared__ float Ws[64 * 128];
    __shared__ float Xs[32 * 128];
    int tid = threadIdx.x;
    int row0 = blockIdx.x * 32;
    for (int i = tid; i < 32 * 128; i += 256) {
        int r = row0 + (i >> 7);
        Xs[i] = (r < nrows) ? X[(size_t)r * 128 + (i & 127)] : 0.f;
    }
    int col = tid & 127, rb = tid >> 7;
    float acc[16];
#pragma unroll
    for (int i = 0; i < 16; i++) acc[i] = 0.f;
    for (int kc = 0; kc < 2; kc++) {
        __syncthreads();
        for (int i = tid; i < 64 * 128; i += 256) Ws[i] = W[kc * 64 * 128 + i];
        __syncthreads();
        for (int k = 0; k < 64; k++) {
            float w = Ws[k * 128 + col];
#pragma unroll
            for (int i = 0; i < 16; i++)
                acc[i] += Xs[(rb + 2 * i) * 128 + kc * 64 + k] * w;
        }
    }
    float bias = b[col];
#pragma unroll
    for (int i = 0; i < 16; i++) {
        int r = row0 + rb + 2 * i;
        if (r < nrows) {
            float v = acc[i] + bias;
            if (RELU) v = fmaxf(v, 0.f);
            Y[(size_t)r * 128 + col] = v;
        }
    }
}

// ---------------------------------------------------------------------------
// K2: B planes (src-side pre-projection), f16 output. Non-persistent:
// one block per 16-node tile (NN divisible by 16 -> no bounds checks).
// ---------------------------------------------------------------------------
__global__ __launch_bounds__(256) void k_preB(
    const float* __restrict__ hbuf, const float* __restrict__ pre_W,
    int layer, __half* __restrict__ Bplanes) {
    __shared__ float Wb[2 * 4 * 32 * 32];  // 32 KB
    __shared__ float Xs[16 * 128];         // 8 KB
    int tid = threadIdx.x;
    for (int i = tid; i < 8192; i += 256) {
        int g = i & 31, f = (i >> 5) & 31, t = (i >> 10) & 3, r = i >> 12;
        Wb[i] = pre_W[((((layer * 2 + r) * 4 + t) * 64) + 32 + f) * 32 + g];
    }
    int r = tid >> 7, c = tid & 127, t = c >> 5, g = c & 31;
    const float* wp = &Wb[((r * 4 + t) * 32) * 32 + g];
    int base = blockIdx.x * 16;
    for (int i = tid; i < 16 * 128; i += 256)
        Xs[i] = hbuf[(size_t)(base + (i >> 7)) * 128 + (i & 127)];
    __syncthreads();
    for (int n = 0; n < 16; n++) {
        float acc = 0.f;
#pragma unroll
        for (int f = 0; f < 32; f++) acc += Xs[n * 128 + t * 32 + f] * wp[f * 32];
        Bplanes[(size_t)r * NN * 128 + (size_t)(base + n) * 128 + c] = __float2half(acc);
    }
}

// ---------------------------------------------------------------------------
// K3: pure gather + B-stats, MFMA-A-packed f16 output. 512 thr = 16 slots x
// 32 g; blockIdx.y = rel*4+tw. Stat ksteps 4+(rel*4+tw)*4..+3; rel0 blocks
// also pack xt kstep=tw straight from hbuf.
// ---------------------------------------------------------------------------
__global__ __launch_bounds__(512) void k_agg_stats(
    const float* __restrict__ hbuf, const __half* __restrict__ Bplanes,
    const int* __restrict__ fwd_nbr, const int* __restrict__ rev_nbr,
    __half* __restrict__ Ap) {
    __shared__ float S[16 * SPAD];
    int tid = threadIdx.x;
    int rel = blockIdx.y >> 2, tw = blockIdx.y & 3;
    const int* nbr = rel ? rev_nbr : fwd_nbr;
    const __half* Bp = Bplanes + (size_t)rel * NN * 128;
    int slot = tid >> 5, g = tid & 31;
    int c = tw * 32 + g;
    int ksS = 4 + (rel * 4 + tw) * 4;
    int packN = rel ? 256 : 320;
    int kl = tid >> 6, lane = tid & 63, mm = lane & 15, quad = lane >> 4;
    for (int rt = blockIdx.x; rt < RT_CNT; rt += gridDim.x) {
        int d = rt * 16 + slot;
        const int4* nb4 = (const int4*)&nbr[d * 8];
        int4 na = nb4[0], nb = nb4[1];
        int idx[8] = {na.x, na.y, na.z, na.w, nb.x, nb.y, nb.z, nb.w};
        float s = 0.f, s2 = 0.f, mn = 1e30f, mx = -1e30f;
#pragma unroll
        for (int k = 0; k < 8; k++) {
            float bv = __half2float(Bp[(size_t)idx[k] * 128 + c]);
            s += bv; s2 += bv * bv; mn = fminf(mn, bv); mx = fmaxf(mx, bv);
        }
        float Bm = s * 0.125f;
        float stdv = sqrtf(fmaxf(s2 * 0.125f - Bm * Bm, 0.f) + 1e-5f);
        float* Sr = &S[slot * SPAD];
        Sr[g] = Bm;
        Sr[32 + g] = mn;
        Sr[64 + g] = mx;
        Sr[96 + g] = stdv;
        __syncthreads();
        if (tid < packN) {
            Pack8 pk;
            int ksD;
            float4 v0, v1;
            if (kl < 4) {
                const float* Sp = &S[mm * SPAD + kl * 32 + quad * 8];
                v0 = *(const float4*)Sp; v1 = *(const float4*)(Sp + 4);
                ksD = ksS + kl;
            } else {  // xt straight from hbuf (rel0 only)
                const float* Hp = &hbuf[(size_t)(rt * 16 + mm) * 128 + tw * 32 + quad * 8];
                v0 = *(const float4*)Hp; v1 = *(const float4*)(Hp + 4);
                ksD = tw;
            }
            pk.h[0] = __float2half(v0.x); pk.h[1] = __float2half(v0.y);
            pk.h[2] = __float2half(v0.z); pk.h[3] = __float2half(v0.w);
            pk.h[4] = __float2half(v1.x); pk.h[5] = __float2half(v1.y);
            pk.h[6] = __float2half(v1.z); pk.h[7] = __float2half(v1.w);
            *(uint4*)&Ap[(((size_t)rt * KSTEPS + ksD) * 64 + lane) * 8] = pk.u;
        }
        __syncthreads();
    }
}

// ---------------------------------------------------------------------------
// K4: MFMA GEMM  stats[N,1152] @ Wc[1152,128] + bc -> ybuf, fused BN sums.
// Pipelined: A-prefetch depth 2 (HBM ~900cy), B depth 1 (L2-hot).
// ---------------------------------------------------------------------------
__global__ __launch_bounds__(256) void k_gemm_mfma(
    const __half* __restrict__ Ap, const __half* __restrict__ Wcp,
    const float* __restrict__ bc, float* __restrict__ Y,
    float* __restrict__ bnsum, float* __restrict__ bnsum2) {
    __shared__ float bnred[256];
    int tid = threadIdx.x;
    bnred[tid] = 0.f;
    __syncthreads();
    int wave = tid >> 6, lane = tid & 63;
    int rt = blockIdx.x * 4 + wave;
    bool active = rt < RT_CNT;
    f32x4 acc[8];
#pragma unroll
    for (int t = 0; t < 8; t++) acc[t] = (f32x4){0.f, 0.f, 0.f, 0.f};
    if (active) {
        const short8* Ab = (const short8*)Ap + (size_t)rt * KSTEPS * 64 + lane;
        const short8* Bb = (const short8*)Wcp + lane;
        short8 aC = Ab[0];
        short8 aN = Ab[64];
        short8 bC[8];
#pragma unroll
        for (int t = 0; t < 8; t++) bC[t] = Bb[(size_t)t * KSTEPS * 64];
#pragma unroll 2
        for (int ks = 0; ks < KSTEPS; ks++) {
            int n1 = (ks + 1 < KSTEPS) ? ks + 1 : 0;
            int n2 = (ks + 2 < KSTEPS) ? ks + 2 : 0;
            short8 aNN = Ab[(size_t)n2 * 64];
            short8 bN[8];
#pragma unroll
            for (int t = 0; t < 8; t++) bN[t] = Bb[((size_t)t * KSTEPS + n1) * 64];
#pragma unroll
            for (int t = 0; t < 8; t++)
                acc[t] = __builtin_amdgcn_mfma_f32_16x16x32_f16(aC, bC[t], acc[t], 0, 0, 0);
            aC = aN; aN = aNN;
#pragma unroll
            for (int t = 0; t < 8; t++) bC[t] = bN[t];
        }
        int nl = lane & 15, quad = lane >> 4;
#pragma unroll
        for (int t = 0; t < 8; t++) {
            int n = t * 16 + nl;
            float bias = bc[n];
            float ls = 0.f, ls2 = 0.f;
#pragma unroll
            for (int r = 0; r < 4; r++) {
                float v = acc[t][r] + bias;
                int node = rt * 16 + quad * 4 + r;
                Y[(size_t)node * 128 + n] = v;
                ls += v; ls2 += v * v;
            }
            ls += __shfl_xor(ls, 16); ls += __shfl_xor(ls, 32);
            ls2 += __shfl_xor(ls2, 16); ls2 += __shfl_xor(ls2, 32);
            if (quad == 0) { atomicAdd(&bnred[n], ls); atomicAdd(&bnred[128 + n], ls2); }
        }
    }
    __syncthreads();
    if (tid < 128) {
        atomicAdd(&bnsum[tid], bnred[tid]);
        atomicAdd(&bnsum2[tid], bnred[128 + tid]);
    }
}

// ---------------------------------------------------------------------------
// K5: BN finalize
// ---------------------------------------------------------------------------
__global__ void k_bn_final(const float* __restrict__ bnsum, const float* __restrict__ bnsum2,
                           const float* __restrict__ gamma, const float* __restrict__ beta,
                           int layer, float* __restrict__ scale, float* __restrict__ shift) {
    int c = threadIdx.x;
    float mu = bnsum[c] * (1.f / NN);
    float var = bnsum2[c] * (1.f / NN) - mu * mu;
    float sc = gamma[layer * 128 + c] * rsqrtf(var + 1e-5f);
    scale[c] = sc;
    shift[c] = beta[layer * 128 + c] - mu * sc;
}

// ---------------------------------------------------------------------------
// K6: apply BN + relu (float4)
// ---------------------------------------------------------------------------
__global__ void k_bn_apply(const float4* __restrict__ y, const float* __restrict__ scale,
                           const float* __restrict__ shift, float4* __restrict__ hout) {
    int i = blockIdx.x * blockDim.x + threadIdx.x;
    if (i >= NN * 32) return;
    int cb = (i & 31) * 4;
    float4 v = y[i];
    v.x = fmaxf(scale[cb + 0] * v.x + shift[cb + 0], 0.f);
    v.y = fmaxf(scale[cb + 1] * v.y + shift[cb + 1], 0.f);
    v.z = fmaxf(scale[cb + 2] * v.z + shift[cb + 2], 0.f);
    v.w = fmaxf(scale[cb + 3] * v.w + shift[cb + 3], 0.f);
    hout[i] = v;
}

// ---------------------------------------------------------------------------
// K7: fused MLP: out = relu(h @ W1 + b1) @ W2 + b2, intermediate in LDS
// ---------------------------------------------------------------------------
__global__ __launch_bounds__(256) void k_mlp(
    const float* __restrict__ X, const float* __restrict__ W1,
    const float* __restrict__ b1, const float* __restrict__ W2,
    const float* __restrict__ b2, float* __restrict__ out, int nrows) {
    __shared__ float Ws[64 * 128];  // 32 KB (reused for W2)
    __shared__ float Xs[32 * 128];  // 16 KB
    __shared__ float T1[32 * 128];  // 16 KB
    int tid = threadIdx.x;
    int row0 = blockIdx.x * 32;
    for (int i = tid; i < 32 * 128; i += 256) {
        int r = row0 + (i >> 7);
        Xs[i] = (r < nrows) ? X[(size_t)r * 128 + (i & 127)] : 0.f;
    }
    int col = tid & 127, rb = tid >> 7;
    float acc[16];
#pragma unroll
    for (int i = 0; i < 16; i++) acc[i] = 0.f;
    for (int kc = 0; kc < 2; kc++) {
        __syncthreads();
        for (int i = tid; i < 64 * 128; i += 256) Ws[i] = W1[kc * 64 * 128 + i];
        __syncthreads();
        for (int k = 0; k < 64; k++) {
            float w = Ws[k * 128 + col];
#pragma unroll
            for (int i = 0; i < 16; i++)
                acc[i] += Xs[(rb + 2 * i) * 128 + kc * 64 + k] * w;
        }
    }
    float bias = b1[col];
#pragma unroll
    for (int i = 0; i < 16; i++)
        T1[(rb + 2 * i) * 128 + col] = fmaxf(acc[i] + bias, 0.f);
    __syncthreads();  // T1 complete; Ws free
    for (int i = tid; i < 128 * 32; i += 256) Ws[i] = W2[i];
    __syncthreads();
    int col2 = tid & 31, rb2 = tid >> 5;
    float acc2[4];
    float bias2 = b2[col2];
#pragma unroll
    for (int i = 0; i < 4; i++) acc2[i] = bias2;
    for (int k = 0; k < 128; k++) {
        float w = Ws[k * 32 + col2];
#pragma unroll
        for (int i = 0; i < 4; i++) acc2[i] += T1[(rb2 + 8 * i) * 128 + k] * w;
    }
#pragma unroll
    for (int i = 0; i < 4; i++) {
        int r = row0 + rb2 + 8 * i;
        if (r < nrows) out[(size_t)r * 32 + col2] = acc2[i];
    }
}

// ---------------------------------------------------------------------------
extern "C" void kernel_launch(void* const* d_in, const int* in_sizes, int n_in,
                              void* d_out, int out_size, void* d_ws, size_t ws_size,
                              hipStream_t stream) {
    const float* x      = (const float*)d_in[0];
    const float* W_in   = (const float*)d_in[1];
    const float* b_in   = (const float*)d_in[2];
    const float* pre_W  = (const float*)d_in[3];
    const float* pre_b  = (const float*)d_in[4];
    const float* post_W = (const float*)d_in[5];
    const float* post_b = (const float*)d_in[6];
    const float* lin_W  = (const float*)d_in[7];
    const float* lin_b  = (const float*)d_in[8];
    const float* bn_g   = (const float*)d_in[9];
    const float* bn_b   = (const float*)d_in[10];
    const float* mlp_W1 = (const float*)d_in[11];
    const float* mlp_b1 = (const float*)d_in[12];
    const float* mlp_W2 = (const float*)d_in[13];
    const float* mlp_b2 = (const float*)d_in[14];
    const int*   edge   = (const int*)d_in[15];
    float* out = (float*)d_out;

    char* w = (char*)d_ws;
    const size_t plane = (size_t)NN * 128 * sizeof(float);       // 25.6 MB
    float* hbuf = (float*)w; w += plane;
    float* ybuf = (float*)w; w += plane;
    __half* Bpl = (__half*)w; w += plane;                        // both rels, f16
    __half* Ap  = (__half*)w; w += (size_t)NN * (KSTEPS * 32) * sizeof(__half);  // 115 MB
    int* fwd_nbr = (int*)w; w += (size_t)NN * DEG * sizeof(int);
    int* rev_nbr = (int*)w; w += (size_t)NN * DEG * sizeof(int);
    int* cnt     = (int*)w; w += (size_t)2 * NN * sizeof(int);
    float* Qw    = (float*)w; w += (size_t)2 * 128 * 128 * sizeof(float);
    float* bc    = (float*)w; w += 2 * 128 * sizeof(float);      // adjacent to Qw
    __half* Wcp  = (__half*)w; w += (size_t)2 * KSTEPS * 32 * 128 * sizeof(__half);
    float* bnsum  = (float*)w; w += 128 * sizeof(float);
    float* bnsum2 = (float*)w; w += 128 * sizeof(float);
    float* scale  = (float*)w; w += 128 * sizeof(float);
    float* shift  = (float*)w; w += 128 * sizeof(float);

    const int gRows = (NN + 31) / 32;  // 1563

    hipMemsetAsync(cnt, 0, (size_t)2 * NN * sizeof(int), stream);
    hipMemsetAsync(Qw, 0, (size_t)(2 * 128 * 128 + 2 * 128) * sizeof(float), stream);
    k_build_nbr<<<(EE + 255) / 256, 256, 0, stream>>>(edge, cnt, fwd_nbr, rev_nbr);
    k_wprep<<<16, 256, 0, stream>>>(post_W, pre_W, pre_b, post_b, lin_W, lin_b,
                                    Wcp, Qw, bc);
    k_pack_xt<<<16, 256, 0, stream>>>(Qw, Wcp);

    // h = relu(x @ W_in + b_in)
    k_gemm128<1><<<gRows, 256, 0, stream>>>(x, W_in, b_in, hbuf, NN);

    for (int l = 0; l < 2; l++) {
        k_preB<<<RT_CNT, 256, 0, stream>>>(hbuf, pre_W, l, Bpl);
        dim3 gag(391, 8);  // y = rel*4 + tower
        k_agg_stats<<<gag, 512, 0, stream>>>(hbuf, Bpl, fwd_nbr, rev_nbr, Ap);
        hipMemsetAsync(bnsum, 0, 2 * 128 * sizeof(float), stream);
        k_gemm_mfma<<<(RT_CNT + 3) / 4, 256, 0, stream>>>(
            Ap, Wcp + (size_t)l * KSTEPS * 32 * 128, bc + l * 128, ybuf, bnsum, bnsum2);
        k_bn_final<<<1, 128, 0, stream>>>(bnsum, bnsum2, bn_g, bn_b, l, scale, shift);
        k_bn_apply<<<(NN * 32 + 255) / 256, 256, 0, stream>>>(
            (const float4*)ybuf, scale, shift, (float4*)hbuf);
    }

    // out = relu(h @ mlp_W1 + b1) @ mlp_W2 + b2   (fused)
    k_mlp<<<gRows, 256, 0, stream>>>(hbuf, mlp_W1, mlp_b1, mlp_W2, mlp_b2, out, NN);
}

// Round 6
// 543.587 us; speedup vs baseline: 1.5803x; 1.2407x over previous
//
#include <hip/hip_runtime.h>
#include <hip/hip_fp16.h>
#include <cstddef>
#include <cstdint>

#define NN 50000
#define DEG 8
#define EE (NN*DEG)
#define RT_CNT 3125   // NN/16 row-tiles
#define KSTEPS 36     // K=1152 / 32:  [xt(4) | (rel,tw) x {Bm,mn,mx,std}(32)]
#define SPAD 132      // stats LDS row pad
#define W8L 18432     // Wcp layer stride in short8 units (KSTEPS*32*128/8)
#define MPAD 136      // f16 tile row pad (halves)

typedef __attribute__((ext_vector_type(8))) short short8;
typedef __attribute__((ext_vector_type(4))) float f32x4;

union Pack8 { __half h[8]; uint4 u; };
union Pack4 { __half h[4]; uint2 u; };

// ---------------------------------------------------------------------------
// K0: build neighbor lists (constant degree 8) via atomic counters
// ---------------------------------------------------------------------------
__global__ void k_build_nbr(const int* __restrict__ ef, int* __restrict__ cnt,
                            int* __restrict__ fwd_nbr, int* __restrict__ rev_nbr) {
    int e = blockIdx.x * blockDim.x + threadIdx.x;
    if (e >= EE) return;
    int s = ef[e], d = ef[EE + e];
    int p = atomicAdd(&cnt[d], 1);
    fwd_nbr[d * DEG + p] = s;
    int q = atomicAdd(&cnt[NN + s], 1);
    rev_nbr[s * DEG + q] = d;
}

// ---------------------------------------------------------------------------
// K0w: combined-weight prep, one block per m4=(l,r,tw). See round-5 notes:
// Pfold folded in LDS; Q = P_xt + Wt@Psum3; T3 = post_b + pre_b@Psum3;
// stat rows -> packed f16 MFMA-B layout; xt partial -> fp32 atomic Qw.
// ---------------------------------------------------------------------------
__global__ __launch_bounds__(256) void k_wprep(
    const float* __restrict__ post_W, const float* __restrict__ pre_W,
    const float* __restrict__ pre_b, const float* __restrict__ post_b,
    const float* __restrict__ lin_W, const float* __restrict__ lin_b,
    __half* __restrict__ Wcp, float* __restrict__ Qw, float* __restrict__ bc) {
    __shared__ float Pf[160 * 33];
    __shared__ float Wl[32 * 128];
    __shared__ float Wt[32 * 32];
    __shared__ float Ps[32 * 32];
    __shared__ float Q[32 * 32];
    __shared__ float T3s[32];
    int tid = threadIdx.x;
    int m4 = blockIdx.x;
    int l = m4 >> 3, r = (m4 >> 2) & 1, tw = m4 & 3;
    const float* PW = post_W + (size_t)m4 * 416 * 32;
    for (int i = tid; i < 160 * 32; i += 256) {
        int row = i >> 5, g = i & 31;
        float v;
        if (row < 32) v = PW[row * 32 + g];
        else {
            int rr = row - 32;
            v = PW[(32 + rr) * 32 + g] + PW[(160 + rr) * 32 + g] + PW[(288 + rr) * 32 + g];
        }
        Pf[row * 33 + g] = v;
    }
    for (int i = tid; i < 1024; i += 256) Wt[i] = pre_W[(size_t)m4 * 2048 + i];
    for (int i = tid; i < 4096; i += 256)
        Wl[i] = lin_W[(size_t)(l * 2 + r) * 16384 + tw * 32 * 128 + i];
    __syncthreads();
    for (int i = tid; i < 1024; i += 256) {
        int g = i >> 5, j = i & 31;
        Ps[i] = Pf[(32 + g) * 33 + j] + Pf[(64 + g) * 33 + j] + Pf[(96 + g) * 33 + j];
    }
    __syncthreads();
    for (int i = tid; i < 1024; i += 256) {
        int f = i >> 5, j = i & 31;
        float acc = Pf[f * 33 + j];
#pragma unroll
        for (int g = 0; g < 32; g++) acc += Wt[f * 32 + g] * Ps[g * 32 + j];
        Q[i] = acc;
    }
    if (tid < 32) {
        int j = tid;
        float v = post_b[m4 * 32 + j];
#pragma unroll
        for (int g = 0; g < 32; g++) v += pre_b[m4 * 32 + g] * Ps[g * 32 + j];
        T3s[j] = v;
    }
    __syncthreads();
    for (int u = tid; u < 2048; u += 256) {
        int lane = u & 63, t = (u >> 6) & 7, s = u >> 9;
        int quad = lane >> 4, nl = lane & 15;
        int n = t * 16 + nl;
        Pack8 pk;
#pragma unroll
        for (int e = 0; e < 8; e++) {
            int f = quad * 8 + e;
            const float* Pr = &Pf[((s + 1) * 32 + f) * 33];
            float acc = 0.f;
#pragma unroll
            for (int j = 0; j < 32; j++) acc += Pr[j] * Wl[j * 128 + n];
            pk.h[e] = __float2half(acc);
        }
        int ks = 4 + r * 16 + tw * 4 + s;
        *(uint4*)&Wcp[((size_t)l * W8L + (t * KSTEPS + ks) * 64 + lane) * 8] = pk.u;
    }
    for (int i = tid; i < 4096; i += 256) {
        int f = i >> 7, n = i & 127;
        float acc = 0.f;
#pragma unroll
        for (int j = 0; j < 32; j++) acc += Q[f * 32 + j] * Wl[j * 128 + n];
        atomicAdd(&Qw[(size_t)l * 16384 + (tw * 32 + f) * 128 + n], acc);
    }
    if (tid < 128) {
        float v = 0.f;
#pragma unroll
        for (int j = 0; j < 32; j++) v += T3s[j] * Wl[j * 128 + tid];
        atomicAdd(&bc[l * 128 + tid], v);
        if ((m4 & 7) == 0)
            atomicAdd(&bc[l * 128 + tid],
                      lin_b[(2 * l) * 128 + tid] + lin_b[(2 * l + 1) * 128 + tid]);
    }
}

// ---------------------------------------------------------------------------
// K0x: pack xt rows (Qw fp32) into Wcp f16 B-frag layout (ks = tw in [0,4))
// ---------------------------------------------------------------------------
__global__ void k_pack_xt(const float* __restrict__ Qw, __half* __restrict__ Wcp) {
    int gid = blockIdx.x * blockDim.x + threadIdx.x;
    if (gid >= 2 * 4 * 8 * 64) return;
    int lane = gid & 63, t = (gid >> 6) & 7, ks = (gid >> 9) & 3, l = gid >> 11;
    int quad = lane >> 4;
    int n = t * 16 + (lane & 15);
    Pack8 pk;
#pragma unroll
    for (int e = 0; e < 8; e++)
        pk.h[e] = __float2half(Qw[(size_t)l * 16384 + (ks * 32 + quad * 8 + e) * 128 + n]);
    *(uint4*)&Wcp[((size_t)l * W8L + (t * KSTEPS + ks) * 64 + lane) * 8] = pk.u;
}

// ---------------------------------------------------------------------------
// K0y: generic fp32 [K][N] -> f16 MFMA-B-frag pack. dst[(t*(K/32)+ks)*64+lane]
// ---------------------------------------------------------------------------
__global__ void k_pack_b(const float* __restrict__ W, int K, int N,
                         __half* __restrict__ dst) {
    int gid = blockIdx.x * blockDim.x + threadIdx.x;
    int total = (K >> 5) * (N >> 4) * 64;
    if (gid >= total) return;
    int lane = gid & 63;
    int ks = (gid >> 6) % (K >> 5);
    int t = (gid >> 6) / (K >> 5);
    int quad = lane >> 4, nl = lane & 15;
    int n = t * 16 + nl;
    Pack8 pk;
#pragma unroll
    for (int e = 0; e < 8; e++)
        pk.h[e] = __float2half(W[(size_t)(ks * 32 + quad * 8 + e) * N + n]);
    *(uint4*)&dst[(size_t)gid * 8] = pk.u;
}

// ---------------------------------------------------------------------------
// K1: input layer via MFMA: h = relu(x @ W_in + b_in). One wave per 16-node
// tile; wave-private LDS segment (no __syncthreads). fp32->f16 staging, b128
// A-frag reads (pad 136), 8 col-tiles MFMA, fp32 scattered epilogue.
// ---------------------------------------------------------------------------
__global__ __launch_bounds__(256) void k_in_mfma(
    const float* __restrict__ X, const __half* __restrict__ Wp,
    const float* __restrict__ b, float* __restrict__ H) {
    __shared__ __half Sh[4][16 * MPAD];
    int tid = threadIdx.x, wave = tid >> 6, lane = tid & 63;
    int rt = blockIdx.x * 4 + wave;
    if (rt >= RT_CNT) rt = RT_CNT - 1;  // redundant recompute, benign
    __half* T = Sh[wave];
    const float4* X4 = (const float4*)X + (size_t)rt * 16 * 32;
#pragma unroll
    for (int i = 0; i < 8; i++) {
        int idx = i * 64 + lane;
        int row = idx >> 5, col4 = idx & 31;
        float4 v = X4[idx];
        Pack4 p4;
        p4.h[0] = __float2half(v.x); p4.h[1] = __float2half(v.y);
        p4.h[2] = __float2half(v.z); p4.h[3] = __float2half(v.w);
        *(uint2*)&T[row * MPAD + col4 * 4] = p4.u;
    }
    int mm = lane & 15, quad = lane >> 4;
    short8 a[4];
#pragma unroll
    for (int ks = 0; ks < 4; ks++)
        a[ks] = *(const short8*)&T[mm * MPAD + ks * 32 + quad * 8];
    const short8* Bb = (const short8*)Wp + lane;
    f32x4 acc[8];
#pragma unroll
    for (int t = 0; t < 8; t++) acc[t] = (f32x4){0.f, 0.f, 0.f, 0.f};
#pragma unroll
    for (int ks = 0; ks < 4; ks++)
#pragma unroll
        for (int t = 0; t < 8; t++)
            acc[t] = __builtin_amdgcn_mfma_f32_16x16x32_f16(
                a[ks], Bb[(t * 4 + ks) * 64], acc[t], 0, 0, 0);
#pragma unroll
    for (int t = 0; t < 8; t++) {
        int n = t * 16 + mm;
        float bias = b[n];
#pragma unroll
        for (int r = 0; r < 4; r++) {
            int node = rt * 16 + quad * 4 + r;
            H[(size_t)node * 128 + n] = fmaxf(acc[t][r] + bias, 0.f);
        }
    }
}

// ---------------------------------------------------------------------------
// K2: B planes (src-side pre-projection), f16 output. Non-persistent.
// ---------------------------------------------------------------------------
__global__ __launch_bounds__(256) void k_preB(
    const float* __restrict__ hbuf, const float* __restrict__ pre_W,
    int layer, __half* __restrict__ Bplanes) {
    __shared__ float Wb[2 * 4 * 32 * 32];  // 32 KB
    __shared__ float Xs[16 * 128];         // 8 KB
    int tid = threadIdx.x;
    for (int i = tid; i < 8192; i += 256) {
        int g = i & 31, f = (i >> 5) & 31, t = (i >> 10) & 3, r = i >> 12;
        Wb[i] = pre_W[((((layer * 2 + r) * 4 + t) * 64) + 32 + f) * 32 + g];
    }
    int r = tid >> 7, c = tid & 127, t = c >> 5, g = c & 31;
    const float* wp = &Wb[((r * 4 + t) * 32) * 32 + g];
    int base = blockIdx.x * 16;
    for (int i = tid; i < 16 * 128; i += 256)
        Xs[i] = hbuf[(size_t)(base + (i >> 7)) * 128 + (i & 127)];
    __syncthreads();
    for (int n = 0; n < 16; n++) {
        float acc = 0.f;
#pragma unroll
        for (int f = 0; f < 32; f++) acc += Xs[n * 128 + t * 32 + f] * wp[f * 32];
        Bplanes[(size_t)r * NN * 128 + (size_t)(base + n) * 128 + c] = __float2half(acc);
    }
}

// ---------------------------------------------------------------------------
// K3: pure gather + B-stats, MFMA-A-packed f16 output. 512 thr = 16 slots x
// 32 g; blockIdx.y = rel*4+tw. Stat ksteps 4+(rel*4+tw)*4..+3; rel0 blocks
// also pack xt kstep=tw straight from hbuf.
// ---------------------------------------------------------------------------
__global__ __launch_bounds__(512) void k_agg_stats(
    const float* __restrict__ hbuf, const __half* __restrict__ Bplanes,
    const int* __restrict__ fwd_nbr, const int* __restrict__ rev_nbr,
    __half* __restrict__ Ap) {
    __shared__ float S[16 * SPAD];
    int tid = threadIdx.x;
    int rel = blockIdx.y >> 2, tw = blockIdx.y & 3;
    const int* nbr = rel ? rev_nbr : fwd_nbr;
    const __half* Bp = Bplanes + (size_t)rel * NN * 128;
    int slot = tid >> 5, g = tid & 31;
    int c = tw * 32 + g;
    int ksS = 4 + (rel * 4 + tw) * 4;
    int packN = rel ? 256 : 320;
    int kl = tid >> 6, lane = tid & 63, mm = lane & 15, quad = lane >> 4;
    for (int rt = blockIdx.x; rt < RT_CNT; rt += gridDim.x) {
        int d = rt * 16 + slot;
        const int4* nb4 = (const int4*)&nbr[d * 8];
        int4 na = nb4[0], nb = nb4[1];
        int idx[8] = {na.x, na.y, na.z, na.w, nb.x, nb.y, nb.z, nb.w};
        float s = 0.f, s2 = 0.f, mn = 1e30f, mx = -1e30f;
#pragma unroll
        for (int k = 0; k < 8; k++) {
            float bv = __half2float(Bp[(size_t)idx[k] * 128 + c]);
            s += bv; s2 += bv * bv; mn = fminf(mn, bv); mx = fmaxf(mx, bv);
        }
        float Bm = s * 0.125f;
        float stdv = sqrtf(fmaxf(s2 * 0.125f - Bm * Bm, 0.f) + 1e-5f);
        float* Sr = &S[slot * SPAD];
        Sr[g] = Bm;
        Sr[32 + g] = mn;
        Sr[64 + g] = mx;
        Sr[96 + g] = stdv;
        __syncthreads();
        if (tid < packN) {
            Pack8 pk;
            int ksD;
            float4 v0, v1;
            if (kl < 4) {
                const float* Sp = &S[mm * SPAD + kl * 32 + quad * 8];
                v0 = *(const float4*)Sp; v1 = *(const float4*)(Sp + 4);
                ksD = ksS + kl;
            } else {  // xt straight from hbuf (rel0 only)
                const float* Hp = &hbuf[(size_t)(rt * 16 + mm) * 128 + tw * 32 + quad * 8];
                v0 = *(const float4*)Hp; v1 = *(const float4*)(Hp + 4);
                ksD = tw;
            }
            pk.h[0] = __float2half(v0.x); pk.h[1] = __float2half(v0.y);
            pk.h[2] = __float2half(v0.z); pk.h[3] = __float2half(v0.w);
            pk.h[4] = __float2half(v1.x); pk.h[5] = __float2half(v1.y);
            pk.h[6] = __float2half(v1.z); pk.h[7] = __float2half(v1.w);
            *(uint4*)&Ap[(((size_t)rt * KSTEPS + ksD) * 64 + lane) * 8] = pk.u;
        }
        __syncthreads();
    }
}

// ---------------------------------------------------------------------------
// K4: MFMA GEMM  stats[N,1152] @ Wc[1152,128] + bc -> ybuf, fused BN sums.
// Pipelined: A-prefetch depth 2 (HBM), B depth 1 (L2-hot).
// ---------------------------------------------------------------------------
__global__ __launch_bounds__(256) void k_gemm_mfma(
    const __half* __restrict__ Ap, const __half* __restrict__ Wcp,
    const float* __restrict__ bc, float* __restrict__ Y,
    float* __restrict__ bnsum, float* __restrict__ bnsum2) {
    __shared__ float bnred[256];
    int tid = threadIdx.x;
    bnred[tid] = 0.f;
    __syncthreads();
    int wave = tid >> 6, lane = tid & 63;
    int rt = blockIdx.x * 4 + wave;
    bool active = rt < RT_CNT;
    f32x4 acc[8];
#pragma unroll
    for (int t = 0; t < 8; t++) acc[t] = (f32x4){0.f, 0.f, 0.f, 0.f};
    if (active) {
        const short8* Ab = (const short8*)Ap + (size_t)rt * KSTEPS * 64 + lane;
        const short8* Bb = (const short8*)Wcp + lane;
        short8 aC = Ab[0];
        short8 aN = Ab[64];
        short8 bC[8];
#pragma unroll
        for (int t = 0; t < 8; t++) bC[t] = Bb[(size_t)t * KSTEPS * 64];
#pragma unroll 2
        for (int ks = 0; ks < KSTEPS; ks++) {
            int n1 = (ks + 1 < KSTEPS) ? ks + 1 : 0;
            int n2 = (ks + 2 < KSTEPS) ? ks + 2 : 0;
            short8 aNN = Ab[(size_t)n2 * 64];
            short8 bN[8];
#pragma unroll
            for (int t = 0; t < 8; t++) bN[t] = Bb[((size_t)t * KSTEPS + n1) * 64];
#pragma unroll
            for (int t = 0; t < 8; t++)
                acc[t] = __builtin_amdgcn_mfma_f32_16x16x32_f16(aC, bC[t], acc[t], 0, 0, 0);
            aC = aN; aN = aNN;
#pragma unroll
            for (int t = 0; t < 8; t++) bC[t] = bN[t];
        }
        int nl = lane & 15, quad = lane >> 4;
#pragma unroll
        for (int t = 0; t < 8; t++) {
            int n = t * 16 + nl;
            float bias = bc[n];
            float ls = 0.f, ls2 = 0.f;
#pragma unroll
            for (int r = 0; r < 4; r++) {
                float v = acc[t][r] + bias;
                int node = rt * 16 + quad * 4 + r;
                Y[(size_t)node * 128 + n] = v;
                ls += v; ls2 += v * v;
            }
            ls += __shfl_xor(ls, 16); ls += __shfl_xor(ls, 32);
            ls2 += __shfl_xor(ls2, 16); ls2 += __shfl_xor(ls2, 32);
            if (quad == 0) { atomicAdd(&bnred[n], ls); atomicAdd(&bnred[128 + n], ls2); }
        }
    }
    __syncthreads();
    if (tid < 128) {
        atomicAdd(&bnsum[tid], bnred[tid]);
        atomicAdd(&bnsum2[tid], bnred[128 + tid]);
    }
}

// ---------------------------------------------------------------------------
// K5: BN finalize
// ---------------------------------------------------------------------------
__global__ void k_bn_final(const float* __restrict__ bnsum, const float* __restrict__ bnsum2,
                           const float* __restrict__ gamma, const float* __restrict__ beta,
                           int layer, float* __restrict__ scale, float* __restrict__ shift) {
    int c = threadIdx.x;
    float mu = bnsum[c] * (1.f / NN);
    float var = bnsum2[c] * (1.f / NN) - mu * mu;
    float sc = gamma[layer * 128 + c] * rsqrtf(var + 1e-5f);
    scale[c] = sc;
    shift[c] = beta[layer * 128 + c] - mu * sc;
}

// ---------------------------------------------------------------------------
// K6: apply BN + relu (float4) — layer 0 only
// ---------------------------------------------------------------------------
__global__ void k_bn_apply(const float4* __restrict__ y, const float* __restrict__ scale,
                           const float* __restrict__ shift, float4* __restrict__ hout) {
    int i = blockIdx.x * blockDim.x + threadIdx.x;
    if (i >= NN * 32) return;
    int cb = (i & 31) * 4;
    float4 v = y[i];
    v.x = fmaxf(scale[cb + 0] * v.x + shift[cb + 0], 0.f);
    v.y = fmaxf(scale[cb + 1] * v.y + shift[cb + 1], 0.f);
    v.z = fmaxf(scale[cb + 2] * v.z + shift[cb + 2], 0.f);
    v.w = fmaxf(scale[cb + 3] * v.w + shift[cb + 3], 0.f);
    hout[i] = v;
}

// ---------------------------------------------------------------------------
// K7: fused BN+relu+MLP via MFMA: out = relu(bn(y) relu'd @ W1 + b1) @ W2 + b2
// One wave per 16-node tile, wave-private LDS (no barriers). T1 round-trips
// through the same LDS tile (in-order DS pipe makes RAW/WAR safe per-wave).
// ---------------------------------------------------------------------------
__global__ __launch_bounds__(256) void k_mlp_mfma(
    const float* __restrict__ Yb, const float* __restrict__ scale,
    const float* __restrict__ shift, const __half* __restrict__ W1p,
    const float* __restrict__ b1, const __half* __restrict__ W2p,
    const float* __restrict__ b2, float* __restrict__ out) {
    __shared__ __half Sh[4][16 * MPAD];
    int tid = threadIdx.x, wave = tid >> 6, lane = tid & 63;
    int rt = blockIdx.x * 4 + wave;
    if (rt >= RT_CNT) rt = RT_CNT - 1;  // redundant recompute, benign
    __half* T = Sh[wave];
    const float4* Y4 = (const float4*)Yb + (size_t)rt * 16 * 32;
    const float4* sc4 = (const float4*)scale;
    const float4* sh4 = (const float4*)shift;
#pragma unroll
    for (int i = 0; i < 8; i++) {
        int idx = i * 64 + lane;
        int row = idx >> 5, col4 = idx & 31;
        float4 v = Y4[idx];
        float4 s = sc4[col4], f = sh4[col4];
        Pack4 p4;
        p4.h[0] = __float2half(fmaxf(s.x * v.x + f.x, 0.f));
        p4.h[1] = __float2half(fmaxf(s.y * v.y + f.y, 0.f));
        p4.h[2] = __float2half(fmaxf(s.z * v.z + f.z, 0.f));
        p4.h[3] = __float2half(fmaxf(s.w * v.w + f.w, 0.f));
        *(uint2*)&T[row * MPAD + col4 * 4] = p4.u;
    }
    int mm = lane & 15, quad = lane >> 4;
    short8 a[4];
#pragma unroll
    for (int ks = 0; ks < 4; ks++)
        a[ks] = *(const short8*)&T[mm * MPAD + ks * 32 + quad * 8];
    const short8* B1 = (const short8*)W1p + lane;
    f32x4 acc[8];
#pragma unroll
    for (int t = 0; t < 8; t++) acc[t] = (f32x4){0.f, 0.f, 0.f, 0.f};
#pragma unroll
    for (int ks = 0; ks < 4; ks++)
#pragma unroll
        for (int t = 0; t < 8; t++)
            acc[t] = __builtin_amdgcn_mfma_f32_16x16x32_f16(
                a[ks], B1[(t * 4 + ks) * 64], acc[t], 0, 0, 0);
    // T1 = relu(acc + b1) -> f16 back into the same LDS tile [m][n]
#pragma unroll
    for (int t = 0; t < 8; t++) {
        int n = t * 16 + mm;
        float bias = b1[n];
#pragma unroll
        for (int r = 0; r < 4; r++)
            T[(quad * 4 + r) * MPAD + n] = __float2half(fmaxf(acc[t][r] + bias, 0.f));
    }
    short8 a2[4];
#pragma unroll
    for (int ks = 0; ks < 4; ks++)
        a2[ks] = *(const short8*)&T[mm * MPAD + ks * 32 + quad * 8];
    const short8* B2 = (const short8*)W2p + lane;
    f32x4 acc2[2];
#pragma unroll
    for (int t = 0; t < 2; t++) acc2[t] = (f32x4){0.f, 0.f, 0.f, 0.f};
#pragma unroll
    for (int ks = 0; ks < 4; ks++)
#pragma unroll
        for (int t = 0; t < 2; t++)
            acc2[t] = __builtin_amdgcn_mfma_f32_16x16x32_f16(
                a2[ks], B2[(t * 4 + ks) * 64], acc2[t], 0, 0, 0);
#pragma unroll
    for (int t = 0; t < 2; t++) {
        int n = t * 16 + mm;
        float bias = b2[n];
#pragma unroll
        for (int r = 0; r < 4; r++)
            out[(size_t)(rt * 16 + quad * 4 + r) * 32 + n] = acc2[t][r] + bias;
    }
}

// ---------------------------------------------------------------------------
extern "C" void kernel_launch(void* const* d_in, const int* in_sizes, int n_in,
                              void* d_out, int out_size, void* d_ws, size_t ws_size,
                              hipStream_t stream) {
    const float* x      = (const float*)d_in[0];
    const float* W_in   = (const float*)d_in[1];
    const float* b_in   = (const float*)d_in[2];
    const float* pre_W  = (const float*)d_in[3];
    const float* pre_b  = (const float*)d_in[4];
    const float* post_W = (const float*)d_in[5];
    const float* post_b = (const float*)d_in[6];
    const float* lin_W  = (const float*)d_in[7];
    const float* lin_b  = (const float*)d_in[8];
    const float* bn_g   = (const float*)d_in[9];
    const float* bn_b   = (const float*)d_in[10];
    const float* mlp_W1 = (const float*)d_in[11];
    const float* mlp_b1 = (const float*)d_in[12];
    const float* mlp_W2 = (const float*)d_in[13];
    const float* mlp_b2 = (const float*)d_in[14];
    const int*   edge   = (const int*)d_in[15];
    float* out = (float*)d_out;

    char* w = (char*)d_ws;
    const size_t plane = (size_t)NN * 128 * sizeof(float);       // 25.6 MB
    float* hbuf = (float*)w; w += plane;
    float* ybuf = (float*)w; w += plane;
    __half* Bpl = (__half*)w; w += plane;                        // both rels, f16
    __half* Ap  = (__half*)w; w += (size_t)NN * (KSTEPS * 32) * sizeof(__half);  // 115 MB
    int* fwd_nbr = (int*)w; w += (size_t)NN * DEG * sizeof(int);
    int* rev_nbr = (int*)w; w += (size_t)NN * DEG * sizeof(int);
    int* cnt     = (int*)w; w += (size_t)2 * NN * sizeof(int);
    float* Qw    = (float*)w; w += (size_t)2 * 128 * 128 * sizeof(float);
    float* bc    = (float*)w; w += 2 * 128 * sizeof(float);      // adjacent to Qw
    __half* Wcp  = (__half*)w; w += (size_t)2 * KSTEPS * 32 * 128 * sizeof(__half);
    __half* Winp = (__half*)w; w += (size_t)128 * 128 * sizeof(__half);
    __half* W1p  = (__half*)w; w += (size_t)128 * 128 * sizeof(__half);
    __half* W2p  = (__half*)w; w += (size_t)128 * 32 * sizeof(__half);
    float* bnsum  = (float*)w; w += 128 * sizeof(float);
    float* bnsum2 = (float*)w; w += 128 * sizeof(float);
    float* scale  = (float*)w; w += 128 * sizeof(float);
    float* shift  = (float*)w; w += 128 * sizeof(float);

    const int gWave = (RT_CNT + 3) / 4;  // 782 blocks (4 waves each)

    hipMemsetAsync(cnt, 0, (size_t)2 * NN * sizeof(int), stream);
    hipMemsetAsync(Qw, 0, (size_t)(2 * 128 * 128 + 2 * 128) * sizeof(float), stream);
    k_build_nbr<<<(EE + 255) / 256, 256, 0, stream>>>(edge, cnt, fwd_nbr, rev_nbr);
    k_wprep<<<16, 256, 0, stream>>>(post_W, pre_W, pre_b, post_b, lin_W, lin_b,
                                    Wcp, Qw, bc);
    k_pack_xt<<<16, 256, 0, stream>>>(Qw, Wcp);
    k_pack_b<<<8, 256, 0, stream>>>(W_in, 128, 128, Winp);
    k_pack_b<<<8, 256, 0, stream>>>(mlp_W1, 128, 128, W1p);
    k_pack_b<<<2, 256, 0, stream>>>(mlp_W2, 128, 32, W2p);

    // h = relu(x @ W_in + b_in)  (MFMA)
    k_in_mfma<<<gWave, 256, 0, stream>>>(x, Winp, b_in, hbuf);

    for (int l = 0; l < 2; l++) {
        k_preB<<<RT_CNT, 256, 0, stream>>>(hbuf, pre_W, l, Bpl);
        dim3 gag(391, 8);  // y = rel*4 + tower
        k_agg_stats<<<gag, 512, 0, stream>>>(hbuf, Bpl, fwd_nbr, rev_nbr, Ap);
        hipMemsetAsync(bnsum, 0, 2 * 128 * sizeof(float), stream);
        k_gemm_mfma<<<gWave, 256, 0, stream>>>(
            Ap, Wcp + (size_t)l * KSTEPS * 32 * 128, bc + l * 128, ybuf, bnsum, bnsum2);
        k_bn_final<<<1, 128, 0, stream>>>(bnsum, bnsum2, bn_g, bn_b, l, scale, shift);
        if (l == 0)
            k_bn_apply<<<(NN * 32 + 255) / 256, 256, 0, stream>>>(
                (const float4*)ybuf, scale, shift, (float4*)hbuf);
    }

    // out = relu(bn_relu(y) @ mlp_W1 + b1) @ mlp_W2 + b2   (fused, MFMA)
    k_mlp_mfma<<<gWave, 256, 0, stream>>>(ybuf, scale, shift, W1p, mlp_b1,
                                          W2p, mlp_b2, out);
}

// Round 7
// 496.666 us; speedup vs baseline: 1.7296x; 1.0945x over previous
//
#include <hip/hip_runtime.h>
#include <hip/hip_fp16.h>
#include <cstddef>
#include <cstdint>

#define NN 50000
#define DEG 8
#define EE (NN*DEG)
#define RT_CNT 3125   // NN/16 row-tiles
#define KSTEPS 36     // K=1152 / 32:  [xt(4) | rel*16+tw*4+{Bm,mn,mx,std}]
#define W8L 18432     // Wcp layer stride in short8 units (KSTEPS*32*128/8)
#define MPAD 136      // f16 tile row pad (halves)

typedef __attribute__((ext_vector_type(8))) short short8;
typedef __attribute__((ext_vector_type(4))) float f32x4;

union Pack8 { __half h[8]; uint4 u; };
union Pack4 { __half h[4]; uint2 u; };

// ---------------------------------------------------------------------------
// K0: build neighbor lists (constant degree 8) via atomic counters
// ---------------------------------------------------------------------------
__global__ void k_build_nbr(const int* __restrict__ ef, int* __restrict__ cnt,
                            int* __restrict__ fwd_nbr, int* __restrict__ rev_nbr) {
    int e = blockIdx.x * blockDim.x + threadIdx.x;
    if (e >= EE) return;
    int s = ef[e], d = ef[EE + e];
    int p = atomicAdd(&cnt[d], 1);
    fwd_nbr[d * DEG + p] = s;
    int q = atomicAdd(&cnt[NN + s], 1);
    rev_nbr[s * DEG + q] = d;
}

// ---------------------------------------------------------------------------
// K0w: combined-weight prep, one block per m4=(l,r,tw). Pfold folded in LDS;
// Q = P_xt + Wt@Psum3; T3 = post_b + pre_b@Psum3; stat rows -> packed f16
// MFMA-B layout; xt partial -> fp32 atomic Qw; bias -> atomic bc.
// ---------------------------------------------------------------------------
__global__ __launch_bounds__(256) void k_wprep(
    const float* __restrict__ post_W, const float* __restrict__ pre_W,
    const float* __restrict__ pre_b, const float* __restrict__ post_b,
    const float* __restrict__ lin_W, const float* __restrict__ lin_b,
    __half* __restrict__ Wcp, float* __restrict__ Qw, float* __restrict__ bc) {
    __shared__ float Pf[160 * 33];
    __shared__ float Wl[32 * 128];
    __shared__ float Wt[32 * 32];
    __shared__ float Ps[32 * 32];
    __shared__ float Q[32 * 32];
    __shared__ float T3s[32];
    int tid = threadIdx.x;
    int m4 = blockIdx.x;
    int l = m4 >> 3, r = (m4 >> 2) & 1, tw = m4 & 3;
    const float* PW = post_W + (size_t)m4 * 416 * 32;
    for (int i = tid; i < 160 * 32; i += 256) {
        int row = i >> 5, g = i & 31;
        float v;
        if (row < 32) v = PW[row * 32 + g];
        else {
            int rr = row - 32;
            v = PW[(32 + rr) * 32 + g] + PW[(160 + rr) * 32 + g] + PW[(288 + rr) * 32 + g];
        }
        Pf[row * 33 + g] = v;
    }
    for (int i = tid; i < 1024; i += 256) Wt[i] = pre_W[(size_t)m4 * 2048 + i];
    for (int i = tid; i < 4096; i += 256)
        Wl[i] = lin_W[(size_t)(l * 2 + r) * 16384 + tw * 32 * 128 + i];
    __syncthreads();
    for (int i = tid; i < 1024; i += 256) {
        int g = i >> 5, j = i & 31;
        Ps[i] = Pf[(32 + g) * 33 + j] + Pf[(64 + g) * 33 + j] + Pf[(96 + g) * 33 + j];
    }
    __syncthreads();
    for (int i = tid; i < 1024; i += 256) {
        int f = i >> 5, j = i & 31;
        float acc = Pf[f * 33 + j];
#pragma unroll
        for (int g = 0; g < 32; g++) acc += Wt[f * 32 + g] * Ps[g * 32 + j];
        Q[i] = acc;
    }
    if (tid < 32) {
        int j = tid;
        float v = post_b[m4 * 32 + j];
#pragma unroll
        for (int g = 0; g < 32; g++) v += pre_b[m4 * 32 + g] * Ps[g * 32 + j];
        T3s[j] = v;
    }
    __syncthreads();
    for (int u = tid; u < 2048; u += 256) {
        int lane = u & 63, t = (u >> 6) & 7, s = u >> 9;
        int quad = lane >> 4, nl = lane & 15;
        int n = t * 16 + nl;
        Pack8 pk;
#pragma unroll
        for (int e = 0; e < 8; e++) {
            int f = quad * 8 + e;
            const float* Pr = &Pf[((s + 1) * 32 + f) * 33];
            float acc = 0.f;
#pragma unroll
            for (int j = 0; j < 32; j++) acc += Pr[j] * Wl[j * 128 + n];
            pk.h[e] = __float2half(acc);
        }
        int ks = 4 + r * 16 + tw * 4 + s;
        *(uint4*)&Wcp[((size_t)l * W8L + (t * KSTEPS + ks) * 64 + lane) * 8] = pk.u;
    }
    for (int i = tid; i < 4096; i += 256) {
        int f = i >> 7, n = i & 127;
        float acc = 0.f;
#pragma unroll
        for (int j = 0; j < 32; j++) acc += Q[f * 32 + j] * Wl[j * 128 + n];
        atomicAdd(&Qw[(size_t)l * 16384 + (tw * 32 + f) * 128 + n], acc);
    }
    if (tid < 128) {
        float v = 0.f;
#pragma unroll
        for (int j = 0; j < 32; j++) v += T3s[j] * Wl[j * 128 + tid];
        atomicAdd(&bc[l * 128 + tid], v);
        if ((m4 & 7) == 0)
            atomicAdd(&bc[l * 128 + tid],
                      lin_b[(2 * l) * 128 + tid] + lin_b[(2 * l + 1) * 128 + tid]);
    }
}

// ---------------------------------------------------------------------------
// K0x: pack xt rows (Qw fp32) into Wcp f16 B-frag layout (ks = tw in [0,4))
// ---------------------------------------------------------------------------
__global__ void k_pack_xt(const float* __restrict__ Qw, __half* __restrict__ Wcp) {
    int gid = blockIdx.x * blockDim.x + threadIdx.x;
    if (gid >= 2 * 4 * 8 * 64) return;
    int lane = gid & 63, t = (gid >> 6) & 7, ks = (gid >> 9) & 3, l = gid >> 11;
    int quad = lane >> 4;
    int n = t * 16 + (lane & 15);
    Pack8 pk;
#pragma unroll
    for (int e = 0; e < 8; e++)
        pk.h[e] = __float2half(Qw[(size_t)l * 16384 + (ks * 32 + quad * 8 + e) * 128 + n]);
    *(uint4*)&Wcp[((size_t)l * W8L + (t * KSTEPS + ks) * 64 + lane) * 8] = pk.u;
}

// ---------------------------------------------------------------------------
// K0y: generic fp32 [K][N] -> f16 MFMA-B-frag pack
// ---------------------------------------------------------------------------
__global__ void k_pack_b(const float* __restrict__ W, int K, int N,
                         __half* __restrict__ dst) {
    int gid = blockIdx.x * blockDim.x + threadIdx.x;
    int total = (K >> 5) * (N >> 4) * 64;
    if (gid >= total) return;
    int lane = gid & 63;
    int ks = (gid >> 6) % (K >> 5);
    int t = (gid >> 6) / (K >> 5);
    int quad = lane >> 4, nl = lane & 15;
    int n = t * 16 + nl;
    Pack8 pk;
#pragma unroll
    for (int e = 0; e < 8; e++)
        pk.h[e] = __float2half(W[(size_t)(ks * 32 + quad * 8 + e) * N + n]);
    *(uint4*)&dst[(size_t)gid * 8] = pk.u;
}

// ---------------------------------------------------------------------------
// K1: input layer via MFMA: h = relu(x @ W_in + b_in). One wave per 16-node
// tile; wave-private LDS segment (no __syncthreads).
// ---------------------------------------------------------------------------
__global__ __launch_bounds__(256) void k_in_mfma(
    const float* __restrict__ X, const __half* __restrict__ Wp,
    const float* __restrict__ b, float* __restrict__ H) {
    __shared__ __half Sh[4][16 * MPAD];
    int tid = threadIdx.x, wave = tid >> 6, lane = tid & 63;
    int rt = blockIdx.x * 4 + wave;
    if (rt >= RT_CNT) rt = RT_CNT - 1;  // redundant recompute, benign
    __half* T = Sh[wave];
    const float4* X4 = (const float4*)X + (size_t)rt * 16 * 32;
#pragma unroll
    for (int i = 0; i < 8; i++) {
        int idx = i * 64 + lane;
        int row = idx >> 5, col4 = idx & 31;
        float4 v = X4[idx];
        Pack4 p4;
        p4.h[0] = __float2half(v.x); p4.h[1] = __float2half(v.y);
        p4.h[2] = __float2half(v.z); p4.h[3] = __float2half(v.w);
        *(uint2*)&T[row * MPAD + col4 * 4] = p4.u;
    }
    int mm = lane & 15, quad = lane >> 4;
    short8 a[4];
#pragma unroll
    for (int ks = 0; ks < 4; ks++)
        a[ks] = *(const short8*)&T[mm * MPAD + ks * 32 + quad * 8];
    const short8* Bb = (const short8*)Wp + lane;
    f32x4 acc[8];
#pragma unroll
    for (int t = 0; t < 8; t++) acc[t] = (f32x4){0.f, 0.f, 0.f, 0.f};
#pragma unroll
    for (int ks = 0; ks < 4; ks++)
#pragma unroll
        for (int t = 0; t < 8; t++)
            acc[t] = __builtin_amdgcn_mfma_f32_16x16x32_f16(
                a[ks], Bb[(t * 4 + ks) * 64], acc[t], 0, 0, 0);
#pragma unroll
    for (int t = 0; t < 8; t++) {
        int n = t * 16 + mm;
        float bias = b[n];
#pragma unroll
        for (int r = 0; r < 4; r++) {
            int node = rt * 16 + quad * 4 + r;
            H[(size_t)node * 128 + n] = fmaxf(acc[t][r] + bias, 0.f);
        }
    }
}

// ---------------------------------------------------------------------------
// K2: B planes (src-side pre-projection), f16 output. Non-persistent.
// ---------------------------------------------------------------------------
__global__ __launch_bounds__(256) void k_preB(
    const float* __restrict__ hbuf, const float* __restrict__ pre_W,
    int layer, __half* __restrict__ Bplanes) {
    __shared__ float Wb[2 * 4 * 32 * 32];  // 32 KB
    __shared__ float Xs[16 * 128];         // 8 KB
    int tid = threadIdx.x;
    for (int i = tid; i < 8192; i += 256) {
        int g = i & 31, f = (i >> 5) & 31, t = (i >> 10) & 3, r = i >> 12;
        Wb[i] = pre_W[((((layer * 2 + r) * 4 + t) * 64) + 32 + f) * 32 + g];
    }
    int r = tid >> 7, c = tid & 127, t = c >> 5, g = c & 31;
    const float* wp = &Wb[((r * 4 + t) * 32) * 32 + g];
    int base = blockIdx.x * 16;
    for (int i = tid; i < 16 * 128; i += 256)
        Xs[i] = hbuf[(size_t)(base + (i >> 7)) * 128 + (i & 127)];
    __syncthreads();
    for (int n = 0; n < 16; n++) {
        float acc = 0.f;
#pragma unroll
        for (int f = 0; f < 32; f++) acc += Xs[n * 128 + t * 32 + f] * wp[f * 32];
        Bplanes[(size_t)r * NN * 128 + (size_t)(base + n) * 128 + c] = __float2half(acc);
    }
}

// ---------------------------------------------------------------------------
// K3: FUSED gather+stats+MFMA-GEMM. One block per 16-node tile.
// Phase A: 4 waves = 4 node-slots; lane covers 2 features via half2 loads of
// full 256-B neighbor rows; raw B-stats (projections folded into Wc) written
// as f16 straight into the LDS A-fragment tile. xt rows packed from hbuf.
// Phase B: 4 waves x 2 col-tiles, 36-kstep MFMA vs L2-hot Wc; Y + BN sums.
// Kills the 230 MB/layer Ap HBM round-trip.
// ---------------------------------------------------------------------------
__global__ __launch_bounds__(256) void k_agg_gemm(
    const float* __restrict__ hbuf, const __half* __restrict__ Bplanes,
    const int* __restrict__ fwd_nbr, const int* __restrict__ rev_nbr,
    const __half* __restrict__ Wcp, const float* __restrict__ bc,
    float* __restrict__ Y, float* __restrict__ bnsum, float* __restrict__ bnsum2) {
    __shared__ __half Spack[KSTEPS * 64 * 8];  // 36,864 B: A-frag tile [ks][lane][8]
    __shared__ float bnred[256];
    int tid = threadIdx.x;
    int blk = blockIdx.x;
    bnred[tid] = 0.f;
    int slot = tid >> 6, lane = tid & 63;
    int c0 = lane * 2;
    int tw = c0 >> 5, o = c0 & 31;
    int quad0 = o >> 3, e0 = o & 7;            // e0 even
    // ---- Phase A: gather + stats ----
    for (int it = 0; it < 4; it++) {
        int m = it * 4 + slot;
        int d = blk * 16 + m;
        int lanep = m + 16 * quad0;
#pragma unroll
        for (int rel = 0; rel < 2; rel++) {
            const int* nb = (rel ? rev_nbr : fwd_nbr) + d * 8;
            const __half* Bp = Bplanes + (size_t)rel * NN * 128;
            int4 na = ((const int4*)nb)[0], nbv = ((const int4*)nb)[1];
            int idx[8] = {na.x, na.y, na.z, na.w, nbv.x, nbv.y, nbv.z, nbv.w};
            __half2 hv[8];
#pragma unroll
            for (int k = 0; k < 8; k++)
                hv[k] = *(const __half2*)&Bp[(size_t)idx[k] * 128 + c0];
            float s0 = 0.f, s1 = 0.f, q0 = 0.f, q1 = 0.f;
            float mn0 = 1e30f, mn1 = 1e30f, mx0 = -1e30f, mx1 = -1e30f;
#pragma unroll
            for (int k = 0; k < 8; k++) {
                float a = __half2float(__low2half(hv[k]));
                float b = __half2float(__high2half(hv[k]));
                s0 += a; q0 += a * a; mn0 = fminf(mn0, a); mx0 = fmaxf(mx0, a);
                s1 += b; q1 += b * b; mn1 = fminf(mn1, b); mx1 = fmaxf(mx1, b);
            }
            float Bm0 = s0 * 0.125f, Bm1 = s1 * 0.125f;
            float sd0 = sqrtf(fmaxf(q0 * 0.125f - Bm0 * Bm0, 0.f) + 1e-5f);
            float sd1 = sqrtf(fmaxf(q1 * 0.125f - Bm1 * Bm1, 0.f) + 1e-5f);
            int ksb = 4 + rel * 16 + tw * 4;
            __half* W0 = &Spack[((ksb * 64 + lanep) * 8) + e0];
            *(__half2*)(W0)             = __halves2half2(__float2half(Bm0), __float2half(Bm1));
            *(__half2*)(W0 + 64 * 8)     = __halves2half2(__float2half(mn0), __float2half(mn1));
            *(__half2*)(W0 + 2 * 64 * 8) = __halves2half2(__float2half(mx0), __float2half(mx1));
            *(__half2*)(W0 + 3 * 64 * 8) = __halves2half2(__float2half(sd0), __float2half(sd1));
        }
    }
    // xt rows (ks = 0..3) straight from hbuf
    for (int u = tid; u < 1024; u += 256) {
        int ep = (u & 3) * 2;
        int ln = (u >> 2) & 63;
        int ks = u >> 8;
        int mm = ln & 15, qd = ln >> 4;
        int c = ks * 32 + qd * 8 + ep;
        const float* Hp = &hbuf[(size_t)(blk * 16 + mm) * 128 + c];
        float2 v = *(const float2*)Hp;
        *(__half2*)&Spack[(ks * 64 + ln) * 8 + ep] =
            __halves2half2(__float2half(v.x), __float2half(v.y));
    }
    __syncthreads();
    // ---- Phase B: MFMA ----
    int wave = tid >> 6;
    int t0 = wave * 2;
    const short8* Bb = (const short8*)Wcp + lane;
    f32x4 acc0 = (f32x4){0.f, 0.f, 0.f, 0.f};
    f32x4 acc1 = (f32x4){0.f, 0.f, 0.f, 0.f};
    short8 b0 = Bb[(size_t)(t0 * KSTEPS) * 64];
    short8 b1 = Bb[(size_t)((t0 + 1) * KSTEPS) * 64];
#pragma unroll 4
    for (int ks = 0; ks < KSTEPS; ks++) {
        short8 a = *(const short8*)&Spack[(ks * 64 + lane) * 8];
        int n1 = (ks + 1 < KSTEPS) ? ks + 1 : 0;
        short8 nb0 = Bb[((size_t)t0 * KSTEPS + n1) * 64];
        short8 nb1 = Bb[(((size_t)t0 + 1) * KSTEPS + n1) * 64];
        acc0 = __builtin_amdgcn_mfma_f32_16x16x32_f16(a, b0, acc0, 0, 0, 0);
        acc1 = __builtin_amdgcn_mfma_f32_16x16x32_f16(a, b1, acc1, 0, 0, 0);
        b0 = nb0; b1 = nb1;
    }
    int nl = lane & 15, quad = lane >> 4;
#pragma unroll
    for (int tt = 0; tt < 2; tt++) {
        f32x4 acc = tt ? acc1 : acc0;
        int n = (t0 + tt) * 16 + nl;
        float bias = bc[n];
        float ls = 0.f, ls2 = 0.f;
#pragma unroll
        for (int r = 0; r < 4; r++) {
            float v = acc[r] + bias;
            int node = blk * 16 + quad * 4 + r;
            Y[(size_t)node * 128 + n] = v;
            ls += v; ls2 += v * v;
        }
        ls += __shfl_xor(ls, 16); ls += __shfl_xor(ls, 32);
        ls2 += __shfl_xor(ls2, 16); ls2 += __shfl_xor(ls2, 32);
        if (quad == 0) { bnred[n] += ls; bnred[128 + n] += ls2; }
    }
    __syncthreads();
    if (tid < 128) {
        atomicAdd(&bnsum[tid], bnred[tid]);
        atomicAdd(&bnsum2[tid], bnred[128 + tid]);
    }
}

// ---------------------------------------------------------------------------
// K5: BN finalize
// ---------------------------------------------------------------------------
__global__ void k_bn_final(const float* __restrict__ bnsum, const float* __restrict__ bnsum2,
                           const float* __restrict__ gamma, const float* __restrict__ beta,
                           int layer, float* __restrict__ scale, float* __restrict__ shift) {
    int c = threadIdx.x;
    float mu = bnsum[c] * (1.f / NN);
    float var = bnsum2[c] * (1.f / NN) - mu * mu;
    float sc = gamma[layer * 128 + c] * rsqrtf(var + 1e-5f);
    scale[c] = sc;
    shift[c] = beta[layer * 128 + c] - mu * sc;
}

// ---------------------------------------------------------------------------
// K6: apply BN + relu (float4) — layer 0 only
// ---------------------------------------------------------------------------
__global__ void k_bn_apply(const float4* __restrict__ y, const float* __restrict__ scale,
                           const float* __restrict__ shift, float4* __restrict__ hout) {
    int i = blockIdx.x * blockDim.x + threadIdx.x;
    if (i >= NN * 32) return;
    int cb = (i & 31) * 4;
    float4 v = y[i];
    v.x = fmaxf(scale[cb + 0] * v.x + shift[cb + 0], 0.f);
    v.y = fmaxf(scale[cb + 1] * v.y + shift[cb + 1], 0.f);
    v.z = fmaxf(scale[cb + 2] * v.z + shift[cb + 2], 0.f);
    v.w = fmaxf(scale[cb + 3] * v.w + shift[cb + 3], 0.f);
    hout[i] = v;
}

// ---------------------------------------------------------------------------
// K7: fused BN+relu+MLP via MFMA (wave-private LDS, no barriers)
// ---------------------------------------------------------------------------
__global__ __launch_bounds__(256) void k_mlp_mfma(
    const float* __restrict__ Yb, const float* __restrict__ scale,
    const float* __restrict__ shift, const __half* __restrict__ W1p,
    const float* __restrict__ b1, const __half* __restrict__ W2p,
    const float* __restrict__ b2, float* __restrict__ out) {
    __shared__ __half Sh[4][16 * MPAD];
    int tid = threadIdx.x, wave = tid >> 6, lane = tid & 63;
    int rt = blockIdx.x * 4 + wave;
    if (rt >= RT_CNT) rt = RT_CNT - 1;  // redundant recompute, benign
    __half* T = Sh[wave];
    const float4* Y4 = (const float4*)Yb + (size_t)rt * 16 * 32;
    const float4* sc4 = (const float4*)scale;
    const float4* sh4 = (const float4*)shift;
#pragma unroll
    for (int i = 0; i < 8; i++) {
        int idx = i * 64 + lane;
        int row = idx >> 5, col4 = idx & 31;
        float4 v = Y4[idx];
        float4 s = sc4[col4], f = sh4[col4];
        Pack4 p4;
        p4.h[0] = __float2half(fmaxf(s.x * v.x + f.x, 0.f));
        p4.h[1] = __float2half(fmaxf(s.y * v.y + f.y, 0.f));
        p4.h[2] = __float2half(fmaxf(s.z * v.z + f.z, 0.f));
        p4.h[3] = __float2half(fmaxf(s.w * v.w + f.w, 0.f));
        *(uint2*)&T[row * MPAD + col4 * 4] = p4.u;
    }
    int mm = lane & 15, quad = lane >> 4;
    short8 a[4];
#pragma unroll
    for (int ks = 0; ks < 4; ks++)
        a[ks] = *(const short8*)&T[mm * MPAD + ks * 32 + quad * 8];
    const short8* B1 = (const short8*)W1p + lane;
    f32x4 acc[8];
#pragma unroll
    for (int t = 0; t < 8; t++) acc[t] = (f32x4){0.f, 0.f, 0.f, 0.f};
#pragma unroll
    for (int ks = 0; ks < 4; ks++)
#pragma unroll
        for (int t = 0; t < 8; t++)
            acc[t] = __builtin_amdgcn_mfma_f32_16x16x32_f16(
                a[ks], B1[(t * 4 + ks) * 64], acc[t], 0, 0, 0);
#pragma unroll
    for (int t = 0; t < 8; t++) {
        int n = t * 16 + mm;
        float bias = b1[n];
#pragma unroll
        for (int r = 0; r < 4; r++)
            T[(quad * 4 + r) * MPAD + n] = __float2half(fmaxf(acc[t][r] + bias, 0.f));
    }
    short8 a2[4];
#pragma unroll
    for (int ks = 0; ks < 4; ks++)
        a2[ks] = *(const short8*)&T[mm * MPAD + ks * 32 + quad * 8];
    const short8* B2 = (const short8*)W2p + lane;
    f32x4 acc2[2];
#pragma unroll
    for (int t = 0; t < 2; t++) acc2[t] = (f32x4){0.f, 0.f, 0.f, 0.f};
#pragma unroll
    for (int ks = 0; ks < 4; ks++)
#pragma unroll
        for (int t = 0; t < 2; t++)
            acc2[t] = __builtin_amdgcn_mfma_f32_16x16x32_f16(
                a2[ks], B2[(t * 4 + ks) * 64], acc2[t], 0, 0, 0);
#pragma unroll
    for (int t = 0; t < 2; t++) {
        int n = t * 16 + mm;
        float bias = b2[t * 16 + mm];
#pragma unroll
        for (int r = 0; r < 4; r++)
            out[(size_t)(rt * 16 + quad * 4 + r) * 32 + n] = acc2[t][r] + bias;
    }
}

// ---------------------------------------------------------------------------
extern "C" void kernel_launch(void* const* d_in, const int* in_sizes, int n_in,
                              void* d_out, int out_size, void* d_ws, size_t ws_size,
                              hipStream_t stream) {
    const float* x      = (const float*)d_in[0];
    const float* W_in   = (const float*)d_in[1];
    const float* b_in   = (const float*)d_in[2];
    const float* pre_W  = (const float*)d_in[3];
    const float* pre_b  = (const float*)d_in[4];
    const float* post_W = (const float*)d_in[5];
    const float* post_b = (const float*)d_in[6];
    const float* lin_W  = (const float*)d_in[7];
    const float* lin_b  = (const float*)d_in[8];
    const float* bn_g   = (const float*)d_in[9];
    const float* bn_b   = (const float*)d_in[10];
    const float* mlp_W1 = (const float*)d_in[11];
    const float* mlp_b1 = (const float*)d_in[12];
    const float* mlp_W2 = (const float*)d_in[13];
    const float* mlp_b2 = (const float*)d_in[14];
    const int*   edge   = (const int*)d_in[15];
    float* out = (float*)d_out;

    char* w = (char*)d_ws;
    const size_t plane = (size_t)NN * 128 * sizeof(float);       // 25.6 MB
    float* hbuf = (float*)w; w += plane;
    float* ybuf = (float*)w; w += plane;
    __half* Bpl = (__half*)w; w += plane;                        // both rels, f16
    int* fwd_nbr = (int*)w; w += (size_t)NN * DEG * sizeof(int);
    int* rev_nbr = (int*)w; w += (size_t)NN * DEG * sizeof(int);
    int* cnt     = (int*)w; w += (size_t)2 * NN * sizeof(int);
    float* Qw    = (float*)w; w += (size_t)2 * 128 * 128 * sizeof(float);
    float* bc    = (float*)w; w += 2 * 128 * sizeof(float);      // adjacent to Qw
    __half* Wcp  = (__half*)w; w += (size_t)2 * KSTEPS * 32 * 128 * sizeof(__half);
    __half* Winp = (__half*)w; w += (size_t)128 * 128 * sizeof(__half);
    __half* W1p  = (__half*)w; w += (size_t)128 * 128 * sizeof(__half);
    __half* W2p  = (__half*)w; w += (size_t)128 * 32 * sizeof(__half);
    float* bnsum  = (float*)w; w += 128 * sizeof(float);
    float* bnsum2 = (float*)w; w += 128 * sizeof(float);
    float* scale  = (float*)w; w += 128 * sizeof(float);
    float* shift  = (float*)w; w += 128 * sizeof(float);

    const int gWave = (RT_CNT + 3) / 4;  // 782 blocks (4 waves each)

    hipMemsetAsync(cnt, 0, (size_t)2 * NN * sizeof(int), stream);
    hipMemsetAsync(Qw, 0, (size_t)(2 * 128 * 128 + 2 * 128) * sizeof(float), stream);
    k_build_nbr<<<(EE + 255) / 256, 256, 0, stream>>>(edge, cnt, fwd_nbr, rev_nbr);
    k_wprep<<<16, 256, 0, stream>>>(post_W, pre_W, pre_b, post_b, lin_W, lin_b,
                                    Wcp, Qw, bc);
    k_pack_xt<<<16, 256, 0, stream>>>(Qw, Wcp);
    k_pack_b<<<8, 256, 0, stream>>>(W_in, 128, 128, Winp);
    k_pack_b<<<8, 256, 0, stream>>>(mlp_W1, 128, 128, W1p);
    k_pack_b<<<2, 256, 0, stream>>>(mlp_W2, 128, 32, W2p);

    // h = relu(x @ W_in + b_in)  (MFMA)
    k_in_mfma<<<gWave, 256, 0, stream>>>(x, Winp, b_in, hbuf);

    for (int l = 0; l < 2; l++) {
        k_preB<<<RT_CNT, 256, 0, stream>>>(hbuf, pre_W, l, Bpl);
        hipMemsetAsync(bnsum, 0, 2 * 128 * sizeof(float), stream);
        k_agg_gemm<<<RT_CNT, 256, 0, stream>>>(
            hbuf, Bpl, fwd_nbr, rev_nbr, Wcp + (size_t)l * KSTEPS * 32 * 128,
            bc + l * 128, ybuf, bnsum, bnsum2);
        k_bn_final<<<1, 128, 0, stream>>>(bnsum, bnsum2, bn_g, bn_b, l, scale, shift);
        if (l == 0)
            k_bn_apply<<<(NN * 32 + 255) / 256, 256, 0, stream>>>(
                (const float4*)ybuf, scale, shift, (float4*)hbuf);
    }

    // out = relu(bn_relu(y) @ mlp_W1 + b1) @ mlp_W2 + b2   (fused, MFMA)
    k_mlp_mfma<<<gWave, 256, 0, stream>>>(ybuf, scale, shift, W1p, mlp_b1,
                                          W2p, mlp_b2, out);
}

// Round 9
// 481.202 us; speedup vs baseline: 1.7852x; 1.0321x over previous
//
#include <hip/hip_runtime.h>
#include <hip/hip_fp16.h>
#include <cstddef>
#include <cstdint>

#define NN 50000
#define DEG 8
#define EE (NN*DEG)
#define RT_CNT 3125   // NN/16 row-tiles
#define KSTEPS 36     // K=1152 / 32:  [xt(4) | rel*16+tw*4+{Bm,mn,mx,std}]
#define W8L 18432     // Wcp layer stride in short8 units (KSTEPS*32*128/8)
#define MPAD 136      // f16 tile row pad (halves)

typedef __attribute__((ext_vector_type(8))) short short8;
typedef __attribute__((ext_vector_type(4))) float f32x4;

union Pack8 { __half h[8]; __half2 h2[4]; uint4 u; };
union Pack4 { __half h[4]; uint2 u; };

// ---------------------------------------------------------------------------
// K0: build neighbor lists (constant degree 8) via atomic counters
// ---------------------------------------------------------------------------
__global__ void k_build_nbr(const int* __restrict__ ef, int* __restrict__ cnt,
                            int* __restrict__ fwd_nbr, int* __restrict__ rev_nbr) {
    int e = blockIdx.x * blockDim.x + threadIdx.x;
    if (e >= EE) return;
    int s = ef[e], d = ef[EE + e];
    int p = atomicAdd(&cnt[d], 1);
    fwd_nbr[d * DEG + p] = s;
    int q = atomicAdd(&cnt[NN + s], 1);
    rev_nbr[s * DEG + q] = d;
}

// ---------------------------------------------------------------------------
// K0w: combined-weight prep, one block per m4=(l,r,tw). Pfold folded in LDS;
// Q = P_xt + Wt@Psum3; T3 = post_b + pre_b@Psum3; stat rows -> packed f16
// MFMA-B layout; xt partial -> fp32 atomic Qw; bias -> atomic bc.
// ---------------------------------------------------------------------------
__global__ __launch_bounds__(256) void k_wprep(
    const float* __restrict__ post_W, const float* __restrict__ pre_W,
    const float* __restrict__ pre_b, const float* __restrict__ post_b,
    const float* __restrict__ lin_W, const float* __restrict__ lin_b,
    __half* __restrict__ Wcp, float* __restrict__ Qw, float* __restrict__ bc) {
    __shared__ float Pf[160 * 33];
    __shared__ float Wl[32 * 128];
    __shared__ float Wt[32 * 32];
    __shared__ float Ps[32 * 32];
    __shared__ float Q[32 * 32];
    __shared__ float T3s[32];
    int tid = threadIdx.x;
    int m4 = blockIdx.x;
    int l = m4 >> 3, r = (m4 >> 2) & 1, tw = m4 & 3;
    const float* PW = post_W + (size_t)m4 * 416 * 32;
    for (int i = tid; i < 160 * 32; i += 256) {
        int row = i >> 5, g = i & 31;
        float v;
        if (row < 32) v = PW[row * 32 + g];
        else {
            int rr = row - 32;
            v = PW[(32 + rr) * 32 + g] + PW[(160 + rr) * 32 + g] + PW[(288 + rr) * 32 + g];
        }
        Pf[row * 33 + g] = v;
    }
    for (int i = tid; i < 1024; i += 256) Wt[i] = pre_W[(size_t)m4 * 2048 + i];
    for (int i = tid; i < 4096; i += 256)
        Wl[i] = lin_W[(size_t)(l * 2 + r) * 16384 + tw * 32 * 128 + i];
    __syncthreads();
    for (int i = tid; i < 1024; i += 256) {
        int g = i >> 5, j = i & 31;
        Ps[i] = Pf[(32 + g) * 33 + j] + Pf[(64 + g) * 33 + j] + Pf[(96 + g) * 33 + j];
    }
    __syncthreads();
    for (int i = tid; i < 1024; i += 256) {
        int f = i >> 5, j = i & 31;
        float acc = Pf[f * 33 + j];
#pragma unroll
        for (int g = 0; g < 32; g++) acc += Wt[f * 32 + g] * Ps[g * 32 + j];
        Q[i] = acc;
    }
    if (tid < 32) {
        int j = tid;
        float v = post_b[m4 * 32 + j];
#pragma unroll
        for (int g = 0; g < 32; g++) v += pre_b[m4 * 32 + g] * Ps[g * 32 + j];
        T3s[j] = v;
    }
    __syncthreads();
    for (int u = tid; u < 2048; u += 256) {
        int lane = u & 63, t = (u >> 6) & 7, s = u >> 9;
        int quad = lane >> 4, nl = lane & 15;
        int n = t * 16 + nl;
        Pack8 pk;
#pragma unroll
        for (int e = 0; e < 8; e++) {
            int f = quad * 8 + e;
            const float* Pr = &Pf[((s + 1) * 32 + f) * 33];
            float acc = 0.f;
#pragma unroll
            for (int j = 0; j < 32; j++) acc += Pr[j] * Wl[j * 128 + n];
            pk.h[e] = __float2half(acc);
        }
        int ks = 4 + r * 16 + tw * 4 + s;
        *(uint4*)&Wcp[((size_t)l * W8L + (t * KSTEPS + ks) * 64 + lane) * 8] = pk.u;
    }
    for (int i = tid; i < 4096; i += 256) {
        int f = i >> 7, n = i & 127;
        float acc = 0.f;
#pragma unroll
        for (int j = 0; j < 32; j++) acc += Q[f * 32 + j] * Wl[j * 128 + n];
        atomicAdd(&Qw[(size_t)l * 16384 + (tw * 32 + f) * 128 + n], acc);
    }
    if (tid < 128) {
        float v = 0.f;
#pragma unroll
        for (int j = 0; j < 32; j++) v += T3s[j] * Wl[j * 128 + tid];
        atomicAdd(&bc[l * 128 + tid], v);
        if ((m4 & 7) == 0)
            atomicAdd(&bc[l * 128 + tid],
                      lin_b[(2 * l) * 128 + tid] + lin_b[(2 * l + 1) * 128 + tid]);
    }
}

// ---------------------------------------------------------------------------
// K0x: pack xt rows (Qw fp32) into Wcp f16 B-frag layout (ks = tw in [0,4))
// ---------------------------------------------------------------------------
__global__ void k_pack_xt(const float* __restrict__ Qw, __half* __restrict__ Wcp) {
    int gid = blockIdx.x * blockDim.x + threadIdx.x;
    if (gid >= 2 * 4 * 8 * 64) return;
    int lane = gid & 63, t = (gid >> 6) & 7, ks = (gid >> 9) & 3, l = gid >> 11;
    int quad = lane >> 4;
    int n = t * 16 + (lane & 15);
    Pack8 pk;
#pragma unroll
    for (int e = 0; e < 8; e++)
        pk.h[e] = __float2half(Qw[(size_t)l * 16384 + (ks * 32 + quad * 8 + e) * 128 + n]);
    *(uint4*)&Wcp[((size_t)l * W8L + (t * KSTEPS + ks) * 64 + lane) * 8] = pk.u;
}

// ---------------------------------------------------------------------------
// K0y: generic fp32 [K][N] -> f16 MFMA-B-frag pack
// ---------------------------------------------------------------------------
__global__ void k_pack_b(const float* __restrict__ W, int K, int N,
                         __half* __restrict__ dst) {
    int gid = blockIdx.x * blockDim.x + threadIdx.x;
    int total = (K >> 5) * (N >> 4) * 64;
    if (gid >= total) return;
    int lane = gid & 63;
    int ks = (gid >> 6) % (K >> 5);
    int t = (gid >> 6) / (K >> 5);
    int quad = lane >> 4, nl = lane & 15;
    int n = t * 16 + nl;
    Pack8 pk;
#pragma unroll
    for (int e = 0; e < 8; e++)
        pk.h[e] = __float2half(W[(size_t)(ks * 32 + quad * 8 + e) * N + n]);
    *(uint4*)&dst[(size_t)gid * 8] = pk.u;
}

// ---------------------------------------------------------------------------
// K1: input layer via MFMA: h = relu(x @ W_in + b_in). One wave per 16-node
// tile; wave-private LDS segment (no __syncthreads).
// ---------------------------------------------------------------------------
__global__ __launch_bounds__(256) void k_in_mfma(
    const float* __restrict__ X, const __half* __restrict__ Wp,
    const float* __restrict__ b, float* __restrict__ H) {
    __shared__ __half Sh[4][16 * MPAD];
    int tid = threadIdx.x, wave = tid >> 6, lane = tid & 63;
    int rt = blockIdx.x * 4 + wave;
    if (rt >= RT_CNT) rt = RT_CNT - 1;  // redundant recompute, benign
    __half* T = Sh[wave];
    const float4* X4 = (const float4*)X + (size_t)rt * 16 * 32;
#pragma unroll
    for (int i = 0; i < 8; i++) {
        int idx = i * 64 + lane;
        int row = idx >> 5, col4 = idx & 31;
        float4 v = X4[idx];
        Pack4 p4;
        p4.h[0] = __float2half(v.x); p4.h[1] = __float2half(v.y);
        p4.h[2] = __float2half(v.z); p4.h[3] = __float2half(v.w);
        *(uint2*)&T[row * MPAD + col4 * 4] = p4.u;
    }
    int mm = lane & 15, quad = lane >> 4;
    short8 a[4];
#pragma unroll
    for (int ks = 0; ks < 4; ks++)
        a[ks] = *(const short8*)&T[mm * MPAD + ks * 32 + quad * 8];
    const short8* Bb = (const short8*)Wp + lane;
    f32x4 acc[8];
#pragma unroll
    for (int t = 0; t < 8; t++) acc[t] = (f32x4){0.f, 0.f, 0.f, 0.f};
#pragma unroll
    for (int ks = 0; ks < 4; ks++)
#pragma unroll
        for (int t = 0; t < 8; t++)
            acc[t] = __builtin_amdgcn_mfma_f32_16x16x32_f16(
                a[ks], Bb[(t * 4 + ks) * 64], acc[t], 0, 0, 0);
#pragma unroll
    for (int t = 0; t < 8; t++) {
        int n = t * 16 + mm;
        float bias = b[n];
#pragma unroll
        for (int r = 0; r < 4; r++) {
            int node = rt * 16 + quad * 4 + r;
            H[(size_t)node * 128 + n] = fmaxf(acc[t][r] + bias, 0.f);
        }
    }
}

// ---------------------------------------------------------------------------
// K2: B planes (src-side pre-projection), f16 output. Non-persistent.
// BN=1 variant also applies scale/shift+relu to the input and writes hbuf
// (fuses the old k_bn_apply pass into layer-1's preB).
// ---------------------------------------------------------------------------
template<int BN>
__global__ __launch_bounds__(256) void k_preB(
    const float* __restrict__ Xin, const float* __restrict__ scale,
    const float* __restrict__ shift, float* __restrict__ hout,
    const float* __restrict__ pre_W, int layer, __half* __restrict__ Bplanes) {
    __shared__ float Wb[2 * 4 * 32 * 32];  // 32 KB
    __shared__ float Xs[16 * 128];         // 8 KB
    int tid = threadIdx.x;
    for (int i = tid; i < 8192; i += 256) {
        int g = i & 31, f = (i >> 5) & 31, t = (i >> 10) & 3, r = i >> 12;
        Wb[i] = pre_W[((((layer * 2 + r) * 4 + t) * 64) + 32 + f) * 32 + g];
    }
    int r = tid >> 7, c = tid & 127, t = c >> 5, g = c & 31;
    const float* wp = &Wb[((r * 4 + t) * 32) * 32 + g];
    int base = blockIdx.x * 16;
    for (int i = tid; i < 16 * 128; i += 256) {
        int col = i & 127;
        size_t gi = (size_t)(base + (i >> 7)) * 128 + col;
        float v = Xin[gi];
        if (BN) {
            v = fmaxf(scale[col] * v + shift[col], 0.f);
            hout[gi] = v;
        }
        Xs[i] = v;
    }
    __syncthreads();
    for (int n = 0; n < 16; n++) {
        float acc = 0.f;
#pragma unroll
        for (int f = 0; f < 32; f++) acc += Xs[n * 128 + t * 32 + f] * wp[f * 32];
        Bplanes[(size_t)r * NN * 128 + (size_t)(base + n) * 128 + c] = __float2half(acc);
    }
}

// ---------------------------------------------------------------------------
// K3: FUSED gather+stats+MFMA-GEMM. One block per 16-node tile.
// Phase A (conflict-free remap): lane L = (m=L&15, q=L>>4); wave w covers
// rel=w>>1, tower-pair w&1. Lane gathers 16-B half8 chunks of its 8 neighbor
// rows (dwordx4, 4 lanes contiguous per row), computes 8-feature stats in
// fp32 (exact for f16 values), stores each stat row as ONE b128 at
// (ks*64+lane): source lane == A-frag lane -> no bank conflicts.
// Phase B: 4 waves x 2 col-tiles, 36-kstep MFMA vs L2-hot Wc; Y + BN sums.
// ---------------------------------------------------------------------------
__global__ __launch_bounds__(256) void k_agg_gemm(
    const float* __restrict__ hbuf, const __half* __restrict__ Bplanes,
    const int* __restrict__ fwd_nbr, const int* __restrict__ rev_nbr,
    const __half* __restrict__ Wcp, const float* __restrict__ bc,
    float* __restrict__ Y, float* __restrict__ bnsum, float* __restrict__ bnsum2) {
    __shared__ __half Spack[KSTEPS * 64 * 8];  // 36,864 B: A-frag tile [ks][lane][8]
    __shared__ float bnred[256];
    int tid = threadIdx.x;
    int blk = blockIdx.x;
    bnred[tid] = 0.f;
    int lane = tid & 63, wv = tid >> 6;
    int m = lane & 15, q = lane >> 4;
    // ---- Phase A: gather + stats ----
    {
        int rel = wv >> 1, twp = (wv & 1) * 2;
        int d = blk * 16 + m;
        const int* nb = (rel ? rev_nbr : fwd_nbr) + d * 8;
        int4 na = ((const int4*)nb)[0], nbv = ((const int4*)nb)[1];
        int idx[8] = {na.x, na.y, na.z, na.w, nbv.x, nbv.y, nbv.z, nbv.w};
        const __half* Bp = Bplanes + (size_t)rel * NN * 128;
#pragma unroll
        for (int t = 0; t < 2; t++) {
            int tw = twp + t;
            Pack8 raw[8];
#pragma unroll
            for (int k = 0; k < 8; k++)
                raw[k].u = *(const uint4*)&Bp[(size_t)idx[k] * 128 + tw * 32 + q * 8];
            float s[8], sq[8], mn[8], mx[8];
#pragma unroll
            for (int j = 0; j < 8; j++) {
                s[j] = 0.f; sq[j] = 0.f; mn[j] = 1e30f; mx[j] = -1e30f;
            }
#pragma unroll
            for (int k = 0; k < 8; k++) {
#pragma unroll
                for (int j = 0; j < 4; j++) {
                    __half2 h = raw[k].h2[j];
                    float a = __half2float(__low2half(h));
                    float b = __half2float(__high2half(h));
                    int j0 = 2 * j, j1 = 2 * j + 1;
                    s[j0] += a; sq[j0] += a * a;
                    mn[j0] = fminf(mn[j0], a); mx[j0] = fmaxf(mx[j0], a);
                    s[j1] += b; sq[j1] += b * b;
                    mn[j1] = fminf(mn[j1], b); mx[j1] = fmaxf(mx[j1], b);
                }
            }
            Pack8 mean, stdv, mnp, mxp;
#pragma unroll
            for (int j = 0; j < 8; j++) {
                float Bm = s[j] * 0.125f;
                mean.h[j] = __float2half(Bm);
                stdv.h[j] = __float2half(
                    sqrtf(fmaxf(sq[j] * 0.125f - Bm * Bm, 0.f) + 1e-5f));
                mnp.h[j] = __float2half(mn[j]);
                mxp.h[j] = __float2half(mx[j]);
            }
            int ksb = 4 + rel * 16 + tw * 4;
            *(uint4*)&Spack[((ksb + 0) * 64 + lane) * 8] = mean.u;
            *(uint4*)&Spack[((ksb + 1) * 64 + lane) * 8] = mnp.u;
            *(uint4*)&Spack[((ksb + 2) * 64 + lane) * 8] = mxp.u;
            *(uint4*)&Spack[((ksb + 3) * 64 + lane) * 8] = stdv.u;
        }
        // xt rows (ks = wv): lane reads its own 8 floats, b128 store
        const float* Hp = &hbuf[(size_t)(blk * 16 + m) * 128 + wv * 32 + q * 8];
        float4 v0 = *(const float4*)Hp;
        float4 v1 = *(const float4*)(Hp + 4);
        Pack8 pk;
        pk.h[0] = __float2half(v0.x); pk.h[1] = __float2half(v0.y);
        pk.h[2] = __float2half(v0.z); pk.h[3] = __float2half(v0.w);
        pk.h[4] = __float2half(v1.x); pk.h[5] = __float2half(v1.y);
        pk.h[6] = __float2half(v1.z); pk.h[7] = __float2half(v1.w);
        *(uint4*)&Spack[(wv * 64 + lane) * 8] = pk.u;
    }
    __syncthreads();
    // ---- Phase B: MFMA ----
    int t0 = wv * 2;
    const short8* Bb = (const short8*)Wcp + lane;
    f32x4 acc0 = (f32x4){0.f, 0.f, 0.f, 0.f};
    f32x4 acc1 = (f32x4){0.f, 0.f, 0.f, 0.f};
    short8 b0 = Bb[(size_t)(t0 * KSTEPS) * 64];
    short8 b1 = Bb[(size_t)((t0 + 1) * KSTEPS) * 64];
#pragma unroll 4
    for (int ks = 0; ks < KSTEPS; ks++) {
        short8 a = *(const short8*)&Spack[(ks * 64 + lane) * 8];
        int n1 = (ks + 1 < KSTEPS) ? ks + 1 : 0;
        short8 nb0 = Bb[((size_t)t0 * KSTEPS + n1) * 64];
        short8 nb1 = Bb[(((size_t)t0 + 1) * KSTEPS + n1) * 64];
        acc0 = __builtin_amdgcn_mfma_f32_16x16x32_f16(a, b0, acc0, 0, 0, 0);
        acc1 = __builtin_amdgcn_mfma_f32_16x16x32_f16(a, b1, acc1, 0, 0, 0);
        b0 = nb0; b1 = nb1;
    }
    int nl = lane & 15, quad = lane >> 4;
#pragma unroll
    for (int tt = 0; tt < 2; tt++) {
        f32x4 acc = tt ? acc1 : acc0;
        int n = (t0 + tt) * 16 + nl;
        float bias = bc[n];
        float ls = 0.f, ls2 = 0.f;
#pragma unroll
        for (int r = 0; r < 4; r++) {
            float v = acc[r] + bias;
            int node = blk * 16 + quad * 4 + r;
            Y[(size_t)node * 128 + n] = v;
            ls += v; ls2 += v * v;
        }
        ls += __shfl_xor(ls, 16); ls += __shfl_xor(ls, 32);
        ls2 += __shfl_xor(ls2, 16); ls2 += __shfl_xor(ls2, 32);
        if (quad == 0) { bnred[n] += ls; bnred[128 + n] += ls2; }
    }
    __syncthreads();
    if (tid < 128) {
        atomicAdd(&bnsum[tid], bnred[tid]);
        atomicAdd(&bnsum2[tid], bnred[128 + tid]);
    }
}

// ---------------------------------------------------------------------------
// K5: BN finalize
// ---------------------------------------------------------------------------
__global__ void k_bn_final(const float* __restrict__ bnsum, const float* __restrict__ bnsum2,
                           const float* __restrict__ gamma, const float* __restrict__ beta,
                           int layer, float* __restrict__ scale, float* __restrict__ shift) {
    int c = threadIdx.x;
    float mu = bnsum[c] * (1.f / NN);
    float var = bnsum2[c] * (1.f / NN) - mu * mu;
    float sc = gamma[layer * 128 + c] * rsqrtf(var + 1e-5f);
    scale[c] = sc;
    shift[c] = beta[layer * 128 + c] - mu * sc;
}

// ---------------------------------------------------------------------------
// K7: fused BN+relu+MLP via MFMA (wave-private LDS, no barriers)
// ---------------------------------------------------------------------------
__global__ __launch_bounds__(256) void k_mlp_mfma(
    const float* __restrict__ Yb, const float* __restrict__ scale,
    const float* __restrict__ shift, const __half* __restrict__ W1p,
    const float* __restrict__ b1, const __half* __restrict__ W2p,
    const float* __restrict__ b2, float* __restrict__ out) {
    __shared__ __half Sh[4][16 * MPAD];
    int tid = threadIdx.x, wave = tid >> 6, lane = tid & 63;
    int rt = blockIdx.x * 4 + wave;
    if (rt >= RT_CNT) rt = RT_CNT - 1;  // redundant recompute, benign
    __half* T = Sh[wave];
    const float4* Y4 = (const float4*)Yb + (size_t)rt * 16 * 32;
    const float4* sc4 = (const float4*)scale;
    const float4* sh4 = (const float4*)shift;
#pragma unroll
    for (int i = 0; i < 8; i++) {
        int idx = i * 64 + lane;
        int row = idx >> 5, col4 = idx & 31;
        float4 v = Y4[idx];
        float4 s = sc4[col4], f = sh4[col4];
        Pack4 p4;
        p4.h[0] = __float2half(fmaxf(s.x * v.x + f.x, 0.f));
        p4.h[1] = __float2half(fmaxf(s.y * v.y + f.y, 0.f));
        p4.h[2] = __float2half(fmaxf(s.z * v.z + f.z, 0.f));
        p4.h[3] = __float2half(fmaxf(s.w * v.w + f.w, 0.f));
        *(uint2*)&T[row * MPAD + col4 * 4] = p4.u;
    }
    int mm = lane & 15, quad = lane >> 4;
    short8 a[4];
#pragma unroll
    for (int ks = 0; ks < 4; ks++)
        a[ks] = *(const short8*)&T[mm * MPAD + ks * 32 + quad * 8];
    const short8* B1 = (const short8*)W1p + lane;
    f32x4 acc[8];
#pragma unroll
    for (int t = 0; t < 8; t++) acc[t] = (f32x4){0.f, 0.f, 0.f, 0.f};
#pragma unroll
    for (int ks = 0; ks < 4; ks++)
#pragma unroll
        for (int t = 0; t < 8; t++)
            acc[t] = __builtin_amdgcn_mfma_f32_16x16x32_f16(
                a[ks], B1[(t * 4 + ks) * 64], acc[t], 0, 0, 0);
#pragma unroll
    for (int t = 0; t < 8; t++) {
        int n = t * 16 + mm;
        float bias = b1[n];
#pragma unroll
        for (int r = 0; r < 4; r++)
            T[(quad * 4 + r) * MPAD + n] = __float2half(fmaxf(acc[t][r] + bias, 0.f));
    }
    short8 a2[4];
#pragma unroll
    for (int ks = 0; ks < 4; ks++)
        a2[ks] = *(const short8*)&T[mm * MPAD + ks * 32 + quad * 8];
    const short8* B2 = (const short8*)W2p + lane;
    f32x4 acc2[2];
#pragma unroll
    for (int t = 0; t < 2; t++) acc2[t] = (f32x4){0.f, 0.f, 0.f, 0.f};
#pragma unroll
    for (int ks = 0; ks < 4; ks++)
#pragma unroll
        for (int t = 0; t < 2; t++)
            acc2[t] = __builtin_amdgcn_mfma_f32_16x16x32_f16(
                a2[ks], B2[(t * 4 + ks) * 64], acc2[t], 0, 0, 0);
#pragma unroll
    for (int t = 0; t < 2; t++) {
        int n = t * 16 + mm;
        float bias = b2[n];
#pragma unroll
        for (int r = 0; r < 4; r++)
            out[(size_t)(rt * 16 + quad * 4 + r) * 32 + n] = acc2[t][r] + bias;
    }
}

// ---------------------------------------------------------------------------
extern "C" void kernel_launch(void* const* d_in, const int* in_sizes, int n_in,
                              void* d_out, int out_size, void* d_ws, size_t ws_size,
                              hipStream_t stream) {
    const float* x      = (const float*)d_in[0];
    const float* W_in   = (const float*)d_in[1];
    const float* b_in   = (const float*)d_in[2];
    const float* pre_W  = (const float*)d_in[3];
    const float* pre_b  = (const float*)d_in[4];
    const float* post_W = (const float*)d_in[5];
    const float* post_b = (const float*)d_in[6];
    const float* lin_W  = (const float*)d_in[7];
    const float* lin_b  = (const float*)d_in[8];
    const float* bn_g   = (const float*)d_in[9];
    const float* bn_b   = (const float*)d_in[10];
    const float* mlp_W1 = (const float*)d_in[11];
    const float* mlp_b1 = (const float*)d_in[12];
    const float* mlp_W2 = (const float*)d_in[13];
    const float* mlp_b2 = (const float*)d_in[14];
    const int*   edge   = (const int*)d_in[15];
    float* out = (float*)d_out;

    char* w = (char*)d_ws;
    const size_t plane = (size_t)NN * 128 * sizeof(float);       // 25.6 MB
    float* hbuf = (float*)w; w += plane;
    float* ybuf = (float*)w; w += plane;
    __half* Bpl = (__half*)w; w += plane;                        // both rels, f16
    int* fwd_nbr = (int*)w; w += (size_t)NN * DEG * sizeof(int);
    int* rev_nbr = (int*)w; w += (size_t)NN * DEG * sizeof(int);
    int* cnt     = (int*)w; w += (size_t)2 * NN * sizeof(int);
    float* Qw    = (float*)w; w += (size_t)2 * 128 * 128 * sizeof(float);
    float* bc    = (float*)w; w += 2 * 128 * sizeof(float);      // adjacent to Qw
    __half* Wcp  = (__half*)w; w += (size_t)2 * KSTEPS * 32 * 128 * sizeof(__half);
    __half* Winp = (__half*)w; w += (size_t)128 * 128 * sizeof(__half);
    __half* W1p  = (__half*)w; w += (size_t)128 * 128 * sizeof(__half);
    __half* W2p  = (__half*)w; w += (size_t)128 * 32 * sizeof(__half);
    float* bnsum  = (float*)w; w += 128 * sizeof(float);
    float* bnsum2 = (float*)w; w += 128 * sizeof(float);
    float* scale  = (float*)w; w += 128 * sizeof(float);
    float* shift  = (float*)w; w += 128 * sizeof(float);

    const int gWave = (RT_CNT + 3) / 4;  // 782 blocks (4 waves each)

    (void)hipMemsetAsync(cnt, 0, (size_t)2 * NN * sizeof(int), stream);
    (void)hipMemsetAsync(Qw, 0, (size_t)(2 * 128 * 128 + 2 * 128) * sizeof(float), stream);
    k_build_nbr<<<(EE + 255) / 256, 256, 0, stream>>>(edge, cnt, fwd_nbr, rev_nbr);
    k_wprep<<<16, 256, 0, stream>>>(post_W, pre_W, pre_b, post_b, lin_W, lin_b,
                                    Wcp, Qw, bc);
    k_pack_xt<<<16, 256, 0, stream>>>(Qw, Wcp);
    k_pack_b<<<8, 256, 0, stream>>>(W_in, 128, 128, Winp);
    k_pack_b<<<8, 256, 0, stream>>>(mlp_W1, 128, 128, W1p);
    k_pack_b<<<2, 256, 0, stream>>>(mlp_W2, 128, 32, W2p);

    // h = relu(x @ W_in + b_in)  (MFMA)
    k_in_mfma<<<gWave, 256, 0, stream>>>(x, Winp, b_in, hbuf);

    for (int l = 0; l < 2; l++) {
        if (l == 0)
            k_preB<0><<<RT_CNT, 256, 0, stream>>>(hbuf, nullptr, nullptr, nullptr,
                                                  pre_W, 0, Bpl);
        else  // fused: h1 = relu(bn(y0)) -> hbuf, plus B planes
            k_preB<1><<<RT_CNT, 256, 0, stream>>>(ybuf, scale, shift, hbuf,
                                                  pre_W, 1, Bpl);
        (void)hipMemsetAsync(bnsum, 0, 2 * 128 * sizeof(float), stream);
        k_agg_gemm<<<RT_CNT, 256, 0, stream>>>(
            hbuf, Bpl, fwd_nbr, rev_nbr, Wcp + (size_t)l * KSTEPS * 32 * 128,
            bc + l * 128, ybuf, bnsum, bnsum2);
        k_bn_final<<<1, 128, 0, stream>>>(bnsum, bnsum2, bn_g, bn_b, l, scale, shift);
    }

    // out = relu(bn_relu(y) @ mlp_W1 + b1) @ mlp_W2 + b2   (fused, MFMA)
    k_mlp_mfma<<<gWave, 256, 0, stream>>>(ybuf, scale, shift, W1p, mlp_b1,
                                          W2p, mlp_b2, out);
}

// Round 10
// 458.297 us; speedup vs baseline: 1.8744x; 1.0500x over previous
//
#include <hip/hip_runtime.h>
#include <hip/hip_fp16.h>
#include <cstddef>
#include <cstdint>

#define NN 50000
#define DEG 8
#define EE (NN*DEG)
#define RT_CNT 3125   // NN/16 row-tiles
#define KSTEPS 36     // K=1152 / 32:  [xt(4) | rel*16+tw*4+{Bm,mn,mx,std}]
#define W8L 18432     // Wcp layer stride in short8 units (KSTEPS*32*128/8)
#define MPAD 136      // f16 tile row pad (halves)

typedef __attribute__((ext_vector_type(8))) short short8;
typedef __attribute__((ext_vector_type(4))) float f32x4;

union Pack8 { __half h[8]; __half2 h2[4]; uint4 u; };
union Pack4 { __half h[4]; uint2 u; };

// ---------------------------------------------------------------------------
// K0: build neighbor lists (constant degree 8) via atomic counters
// ---------------------------------------------------------------------------
__global__ void k_build_nbr(const int* __restrict__ ef, int* __restrict__ cnt,
                            int* __restrict__ fwd_nbr, int* __restrict__ rev_nbr) {
    int e = blockIdx.x * blockDim.x + threadIdx.x;
    if (e >= EE) return;
    int s = ef[e], d = ef[EE + e];
    int p = atomicAdd(&cnt[d], 1);
    fwd_nbr[d * DEG + p] = s;
    int q = atomicAdd(&cnt[NN + s], 1);
    rev_nbr[s * DEG + q] = d;
}

// ---------------------------------------------------------------------------
// K0w: combined-weight prep, one block per m4=(l,r,tw). Pfold folded in LDS;
// Q = P_xt + Wt@Psum3; T3 = post_b + pre_b@Psum3; stat rows -> packed f16
// MFMA-B layout; xt partial -> fp32 atomic Qw; bias -> atomic bc.
// ---------------------------------------------------------------------------
__global__ __launch_bounds__(256) void k_wprep(
    const float* __restrict__ post_W, const float* __restrict__ pre_W,
    const float* __restrict__ pre_b, const float* __restrict__ post_b,
    const float* __restrict__ lin_W, const float* __restrict__ lin_b,
    __half* __restrict__ Wcp, float* __restrict__ Qw, float* __restrict__ bc) {
    __shared__ float Pf[160 * 33];
    __shared__ float Wl[32 * 128];
    __shared__ float Wt[32 * 32];
    __shared__ float Ps[32 * 32];
    __shared__ float Q[32 * 32];
    __shared__ float T3s[32];
    int tid = threadIdx.x;
    int m4 = blockIdx.x;
    int l = m4 >> 3, r = (m4 >> 2) & 1, tw = m4 & 3;
    const float* PW = post_W + (size_t)m4 * 416 * 32;
    for (int i = tid; i < 160 * 32; i += 256) {
        int row = i >> 5, g = i & 31;
        float v;
        if (row < 32) v = PW[row * 32 + g];
        else {
            int rr = row - 32;
            v = PW[(32 + rr) * 32 + g] + PW[(160 + rr) * 32 + g] + PW[(288 + rr) * 32 + g];
        }
        Pf[row * 33 + g] = v;
    }
    for (int i = tid; i < 1024; i += 256) Wt[i] = pre_W[(size_t)m4 * 2048 + i];
    for (int i = tid; i < 4096; i += 256)
        Wl[i] = lin_W[(size_t)(l * 2 + r) * 16384 + tw * 32 * 128 + i];
    __syncthreads();
    for (int i = tid; i < 1024; i += 256) {
        int g = i >> 5, j = i & 31;
        Ps[i] = Pf[(32 + g) * 33 + j] + Pf[(64 + g) * 33 + j] + Pf[(96 + g) * 33 + j];
    }
    __syncthreads();
    for (int i = tid; i < 1024; i += 256) {
        int f = i >> 5, j = i & 31;
        float acc = Pf[f * 33 + j];
#pragma unroll
        for (int g = 0; g < 32; g++) acc += Wt[f * 32 + g] * Ps[g * 32 + j];
        Q[i] = acc;
    }
    if (tid < 32) {
        int j = tid;
        float v = post_b[m4 * 32 + j];
#pragma unroll
        for (int g = 0; g < 32; g++) v += pre_b[m4 * 32 + g] * Ps[g * 32 + j];
        T3s[j] = v;
    }
    __syncthreads();
    for (int u = tid; u < 2048; u += 256) {
        int lane = u & 63, t = (u >> 6) & 7, s = u >> 9;
        int quad = lane >> 4, nl = lane & 15;
        int n = t * 16 + nl;
        Pack8 pk;
#pragma unroll
        for (int e = 0; e < 8; e++) {
            int f = quad * 8 + e;
            const float* Pr = &Pf[((s + 1) * 32 + f) * 33];
            float acc = 0.f;
#pragma unroll
            for (int j = 0; j < 32; j++) acc += Pr[j] * Wl[j * 128 + n];
            pk.h[e] = __float2half(acc);
        }
        int ks = 4 + r * 16 + tw * 4 + s;
        *(uint4*)&Wcp[((size_t)l * W8L + (t * KSTEPS + ks) * 64 + lane) * 8] = pk.u;
    }
    for (int i = tid; i < 4096; i += 256) {
        int f = i >> 7, n = i & 127;
        float acc = 0.f;
#pragma unroll
        for (int j = 0; j < 32; j++) acc += Q[f * 32 + j] * Wl[j * 128 + n];
        atomicAdd(&Qw[(size_t)l * 16384 + (tw * 32 + f) * 128 + n], acc);
    }
    if (tid < 128) {
        float v = 0.f;
#pragma unroll
        for (int j = 0; j < 32; j++) v += T3s[j] * Wl[j * 128 + tid];
        atomicAdd(&bc[l * 128 + tid], v);
        if ((m4 & 7) == 0)
            atomicAdd(&bc[l * 128 + tid],
                      lin_b[(2 * l) * 128 + tid] + lin_b[(2 * l + 1) * 128 + tid]);
    }
}

// ---------------------------------------------------------------------------
// K0x: pack xt rows (Qw fp32) into Wcp f16 B-frag layout (ks = tw in [0,4))
// ---------------------------------------------------------------------------
__global__ void k_pack_xt(const float* __restrict__ Qw, __half* __restrict__ Wcp) {
    int gid = blockIdx.x * blockDim.x + threadIdx.x;
    if (gid >= 2 * 4 * 8 * 64) return;
    int lane = gid & 63, t = (gid >> 6) & 7, ks = (gid >> 9) & 3, l = gid >> 11;
    int quad = lane >> 4;
    int n = t * 16 + (lane & 15);
    Pack8 pk;
#pragma unroll
    for (int e = 0; e < 8; e++)
        pk.h[e] = __float2half(Qw[(size_t)l * 16384 + (ks * 32 + quad * 8 + e) * 128 + n]);
    *(uint4*)&Wcp[((size_t)l * W8L + (t * KSTEPS + ks) * 64 + lane) * 8] = pk.u;
}

// ---------------------------------------------------------------------------
// K0y: generic fp32 [K][N] -> f16 MFMA-B-frag pack
// ---------------------------------------------------------------------------
__global__ void k_pack_b(const float* __restrict__ W, int K, int N,
                         __half* __restrict__ dst) {
    int gid = blockIdx.x * blockDim.x + threadIdx.x;
    int total = (K >> 5) * (N >> 4) * 64;
    if (gid >= total) return;
    int lane = gid & 63;
    int ks = (gid >> 6) % (K >> 5);
    int t = (gid >> 6) / (K >> 5);
    int quad = lane >> 4, nl = lane & 15;
    int n = t * 16 + nl;
    Pack8 pk;
#pragma unroll
    for (int e = 0; e < 8; e++)
        pk.h[e] = __float2half(W[(size_t)(ks * 32 + quad * 8 + e) * N + n]);
    *(uint4*)&dst[(size_t)gid * 8] = pk.u;
}

// ---------------------------------------------------------------------------
// K1: input layer via MFMA: h = relu(x @ W_in + b_in). One wave per 16-node
// tile; wave-private LDS segment (no __syncthreads).
// ---------------------------------------------------------------------------
__global__ __launch_bounds__(256) void k_in_mfma(
    const float* __restrict__ X, const __half* __restrict__ Wp,
    const float* __restrict__ b, float* __restrict__ H) {
    __shared__ __half Sh[4][16 * MPAD];
    int tid = threadIdx.x, wave = tid >> 6, lane = tid & 63;
    int rt = blockIdx.x * 4 + wave;
    if (rt >= RT_CNT) rt = RT_CNT - 1;  // redundant recompute, benign
    __half* T = Sh[wave];
    const float4* X4 = (const float4*)X + (size_t)rt * 16 * 32;
#pragma unroll
    for (int i = 0; i < 8; i++) {
        int idx = i * 64 + lane;
        int row = idx >> 5, col4 = idx & 31;
        float4 v = X4[idx];
        Pack4 p4;
        p4.h[0] = __float2half(v.x); p4.h[1] = __float2half(v.y);
        p4.h[2] = __float2half(v.z); p4.h[3] = __float2half(v.w);
        *(uint2*)&T[row * MPAD + col4 * 4] = p4.u;
    }
    int mm = lane & 15, quad = lane >> 4;
    short8 a[4];
#pragma unroll
    for (int ks = 0; ks < 4; ks++)
        a[ks] = *(const short8*)&T[mm * MPAD + ks * 32 + quad * 8];
    const short8* Bb = (const short8*)Wp + lane;
    f32x4 acc[8];
#pragma unroll
    for (int t = 0; t < 8; t++) acc[t] = (f32x4){0.f, 0.f, 0.f, 0.f};
#pragma unroll
    for (int ks = 0; ks < 4; ks++)
#pragma unroll
        for (int t = 0; t < 8; t++)
            acc[t] = __builtin_amdgcn_mfma_f32_16x16x32_f16(
                a[ks], Bb[(t * 4 + ks) * 64], acc[t], 0, 0, 0);
#pragma unroll
    for (int t = 0; t < 8; t++) {
        int n = t * 16 + mm;
        float bias = b[n];
#pragma unroll
        for (int r = 0; r < 4; r++) {
            int node = rt * 16 + quad * 4 + r;
            H[(size_t)node * 128 + n] = fmaxf(acc[t][r] + bias, 0.f);
        }
    }
}

// ---------------------------------------------------------------------------
// K2: B planes (src-side pre-projection), f16 output. Non-persistent.
// BN=1 variant also applies scale/shift+relu to the input and writes hbuf.
// ---------------------------------------------------------------------------
template<int BN>
__global__ __launch_bounds__(256) void k_preB(
    const float* __restrict__ Xin, const float* __restrict__ scale,
    const float* __restrict__ shift, float* __restrict__ hout,
    const float* __restrict__ pre_W, int layer, __half* __restrict__ Bplanes) {
    __shared__ float Wb[2 * 4 * 32 * 32];  // 32 KB
    __shared__ float Xs[16 * 128];         // 8 KB
    int tid = threadIdx.x;
    for (int i = tid; i < 8192; i += 256) {
        int g = i & 31, f = (i >> 5) & 31, t = (i >> 10) & 3, r = i >> 12;
        Wb[i] = pre_W[((((layer * 2 + r) * 4 + t) * 64) + 32 + f) * 32 + g];
    }
    int r = tid >> 7, c = tid & 127, t = c >> 5, g = c & 31;
    const float* wp = &Wb[((r * 4 + t) * 32) * 32 + g];
    int base = blockIdx.x * 16;
    for (int i = tid; i < 16 * 128; i += 256) {
        int col = i & 127;
        size_t gi = (size_t)(base + (i >> 7)) * 128 + col;
        float v = Xin[gi];
        if (BN) {
            v = fmaxf(scale[col] * v + shift[col], 0.f);
            hout[gi] = v;
        }
        Xs[i] = v;
    }
    __syncthreads();
    for (int n = 0; n < 16; n++) {
        float acc = 0.f;
#pragma unroll
        for (int f = 0; f < 32; f++) acc += Xs[n * 128 + t * 32 + f] * wp[f * 32];
        Bplanes[(size_t)r * NN * 128 + (size_t)(base + n) * 128 + c] = __float2half(acc);
    }
}

// ---------------------------------------------------------------------------
// K3: FUSED gather+stats+MFMA-GEMM. One block per 16-node tile.
// Phase A (256-B granule): lane = (s = dst-slot L>>4, f16 = L&15); 16
// consecutive lanes read one FULL 256-B neighbor row per instruction (4 rows
// per instr). Stats accumulate fully in-lane (8 features). Spack stores use
// XOR swizzle pos = 16q + (m^q^((tw&1)<<2)) -> uniform bank spread; phase-B
// reads use the same bijection (0 conflicts).
// Phase B: depth-6 register prefetch of B frags (covers L2 latency).
// ---------------------------------------------------------------------------
__global__ __launch_bounds__(256, 4) void k_agg_gemm(
    const float* __restrict__ hbuf, const __half* __restrict__ Bplanes,
    const int* __restrict__ fwd_nbr, const int* __restrict__ rev_nbr,
    const __half* __restrict__ Wcp, const float* __restrict__ bc,
    float* __restrict__ Y, float* __restrict__ bnsum, float* __restrict__ bnsum2) {
    __shared__ __half Spack[KSTEPS * 64 * 8];  // 36,864 B
    __shared__ float bnred[256];
    int tid = threadIdx.x;
    int blk = blockIdx.x;
    bnred[tid] = 0.f;
    int lane = tid & 63, wv = tid >> 6;
    int s = lane >> 4, f16 = lane & 15;
    int tw = f16 >> 2, quad = f16 & 3;
    int m = wv * 4 + s;                 // dst slot 0..15 (gather role)
    int d = blk * 16 + m;
    // ---- Phase A: gather (256-B granule) + in-lane stats ----
    {
        const int4* nf = (const int4*)&fwd_nbr[d * 8];
        const int4* nr = (const int4*)&rev_nbr[d * 8];
        int4 a0 = nf[0], a1 = nf[1], b0v = nr[0], b1v = nr[1];
        int idx0[8] = {a0.x, a0.y, a0.z, a0.w, a1.x, a1.y, a1.z, a1.w};
        int idx1[8] = {b0v.x, b0v.y, b0v.z, b0v.w, b1v.x, b1v.y, b1v.z, b1v.w};
        int fo = f16 * 8;               // feature offset (halves)
        Pack8 r0[8], r1[8];
        const __half* Bp1 = Bplanes + (size_t)NN * 128;
#pragma unroll
        for (int k = 0; k < 8; k++)
            r0[k].u = *(const uint4*)&Bplanes[(size_t)idx0[k] * 128 + fo];
#pragma unroll
        for (int k = 0; k < 8; k++)
            r1[k].u = *(const uint4*)&Bp1[(size_t)idx1[k] * 128 + fo];
        // xt row (ks = wv): logical (node=f16, quad=s)
        const float* Hp = &hbuf[(size_t)(blk * 16 + f16) * 128 + wv * 32 + s * 8];
        float4 xv0 = *(const float4*)Hp;
        float4 xv1 = *(const float4*)(Hp + 4);
        int pos = 16 * quad + (m ^ quad ^ ((tw & 1) << 2));
#pragma unroll
        for (int rel = 0; rel < 2; rel++) {
            Pack8* rr = rel ? r1 : r0;
            float sS[8], qS[8], mnS[8], mxS[8];
#pragma unroll
            for (int j = 0; j < 8; j++) {
                sS[j] = 0.f; qS[j] = 0.f; mnS[j] = 1e30f; mxS[j] = -1e30f;
            }
#pragma unroll
            for (int k = 0; k < 8; k++) {
#pragma unroll
                for (int j2 = 0; j2 < 4; j2++) {
                    __half2 h = rr[k].h2[j2];
                    float a = __half2float(__low2half(h));
                    float b = __half2float(__high2half(h));
                    int j0 = 2 * j2, j1 = j0 + 1;
                    sS[j0] += a; qS[j0] += a * a;
                    mnS[j0] = fminf(mnS[j0], a); mxS[j0] = fmaxf(mxS[j0], a);
                    sS[j1] += b; qS[j1] += b * b;
                    mnS[j1] = fminf(mnS[j1], b); mxS[j1] = fmaxf(mxS[j1], b);
                }
            }
            Pack8 mean, stdv, mnp, mxp;
#pragma unroll
            for (int j = 0; j < 8; j++) {
                float Bm = sS[j] * 0.125f;
                mean.h[j] = __float2half(Bm);
                stdv.h[j] = __float2half(
                    sqrtf(fmaxf(qS[j] * 0.125f - Bm * Bm, 0.f) + 1e-5f));
                mnp.h[j] = __float2half(mnS[j]);
                mxp.h[j] = __float2half(mxS[j]);
            }
            int ksb = 4 + rel * 16 + tw * 4;
            *(uint4*)&Spack[((size_t)(ksb + 0) * 64 + pos) * 8] = mean.u;
            *(uint4*)&Spack[((size_t)(ksb + 1) * 64 + pos) * 8] = mnp.u;
            *(uint4*)&Spack[((size_t)(ksb + 2) * 64 + pos) * 8] = mxp.u;
            *(uint4*)&Spack[((size_t)(ksb + 3) * 64 + pos) * 8] = stdv.u;
        }
        // xt store: logical (m=f16, quad=s), row ks=wv -> par = wv&1
        int posx = 16 * s + (f16 ^ s ^ ((wv & 1) << 2));
        Pack8 pk;
        pk.h[0] = __float2half(xv0.x); pk.h[1] = __float2half(xv0.y);
        pk.h[2] = __float2half(xv0.z); pk.h[3] = __float2half(xv0.w);
        pk.h[4] = __float2half(xv1.x); pk.h[5] = __float2half(xv1.y);
        pk.h[6] = __float2half(xv1.z); pk.h[7] = __float2half(xv1.w);
        *(uint4*)&Spack[((size_t)wv * 64 + posx) * 8] = pk.u;
    }
    __syncthreads();
    // ---- Phase B: MFMA with depth-6 B prefetch ----
    int mB = lane & 15, qB = lane >> 4;
    int t0 = wv * 2;
    const short8* Bb = (const short8*)Wcp + lane;
    f32x4 acc0 = (f32x4){0.f, 0.f, 0.f, 0.f};
    f32x4 acc1 = (f32x4){0.f, 0.f, 0.f, 0.f};
    short8 p0[6], p1[6];
#pragma unroll
    for (int dd = 0; dd < 6; dd++) {
        p0[dd] = Bb[((size_t)t0 * KSTEPS + dd) * 64];
        p1[dd] = Bb[((size_t)(t0 + 1) * KSTEPS + dd) * 64];
    }
#pragma unroll
    for (int ks = 0; ks < KSTEPS; ks++) {
        int twk = (ks < 4) ? ks : (((ks - 4) >> 2) & 3);
        int pos = 16 * qB + (mB ^ qB ^ ((twk & 1) << 2));
        short8 a = *(const short8*)&Spack[((size_t)ks * 64 + pos) * 8];
        acc0 = __builtin_amdgcn_mfma_f32_16x16x32_f16(a, p0[ks % 6], acc0, 0, 0, 0);
        acc1 = __builtin_amdgcn_mfma_f32_16x16x32_f16(a, p1[ks % 6], acc1, 0, 0, 0);
        if (ks + 6 < KSTEPS) {
            p0[ks % 6] = Bb[((size_t)t0 * KSTEPS + ks + 6) * 64];
            p1[ks % 6] = Bb[((size_t)(t0 + 1) * KSTEPS + ks + 6) * 64];
        }
    }
    int nl = lane & 15, qd = lane >> 4;
#pragma unroll
    for (int tt = 0; tt < 2; tt++) {
        f32x4 acc = tt ? acc1 : acc0;
        int n = (t0 + tt) * 16 + nl;
        float bias = bc[n];
        float ls = 0.f, ls2 = 0.f;
#pragma unroll
        for (int r = 0; r < 4; r++) {
            float v = acc[r] + bias;
            int node = blk * 16 + qd * 4 + r;
            Y[(size_t)node * 128 + n] = v;
            ls += v; ls2 += v * v;
        }
        ls += __shfl_xor(ls, 16); ls += __shfl_xor(ls, 32);
        ls2 += __shfl_xor(ls2, 16); ls2 += __shfl_xor(ls2, 32);
        if (qd == 0) { bnred[n] += ls; bnred[128 + n] += ls2; }
    }
    __syncthreads();
    if (tid < 128) {
        atomicAdd(&bnsum[tid], bnred[tid]);
        atomicAdd(&bnsum2[tid], bnred[128 + tid]);
    }
}

// ---------------------------------------------------------------------------
// K5: BN finalize
// ---------------------------------------------------------------------------
__global__ void k_bn_final(const float* __restrict__ bnsum, const float* __restrict__ bnsum2,
                           const float* __restrict__ gamma, const float* __restrict__ beta,
                           int layer, float* __restrict__ scale, float* __restrict__ shift) {
    int c = threadIdx.x;
    float mu = bnsum[c] * (1.f / NN);
    float var = bnsum2[c] * (1.f / NN) - mu * mu;
    float sc = gamma[layer * 128 + c] * rsqrtf(var + 1e-5f);
    scale[c] = sc;
    shift[c] = beta[layer * 128 + c] - mu * sc;
}

// ---------------------------------------------------------------------------
// K7: fused BN+relu+MLP via MFMA (wave-private LDS, no barriers)
// ---------------------------------------------------------------------------
__global__ __launch_bounds__(256) void k_mlp_mfma(
    const float* __restrict__ Yb, const float* __restrict__ scale,
    const float* __restrict__ shift, const __half* __restrict__ W1p,
    const float* __restrict__ b1, const __half* __restrict__ W2p,
    const float* __restrict__ b2, float* __restrict__ out) {
    __shared__ __half Sh[4][16 * MPAD];
    int tid = threadIdx.x, wave = tid >> 6, lane = tid & 63;
    int rt = blockIdx.x * 4 + wave;
    if (rt >= RT_CNT) rt = RT_CNT - 1;  // redundant recompute, benign
    __half* T = Sh[wave];
    const float4* Y4 = (const float4*)Yb + (size_t)rt * 16 * 32;
    const float4* sc4 = (const float4*)scale;
    const float4* sh4 = (const float4*)shift;
#pragma unroll
    for (int i = 0; i < 8; i++) {
        int idx = i * 64 + lane;
        int row = idx >> 5, col4 = idx & 31;
        float4 v = Y4[idx];
        float4 s = sc4[col4], f = sh4[col4];
        Pack4 p4;
        p4.h[0] = __float2half(fmaxf(s.x * v.x + f.x, 0.f));
        p4.h[1] = __float2half(fmaxf(s.y * v.y + f.y, 0.f));
        p4.h[2] = __float2half(fmaxf(s.z * v.z + f.z, 0.f));
        p4.h[3] = __float2half(fmaxf(s.w * v.w + f.w, 0.f));
        *(uint2*)&T[row * MPAD + col4 * 4] = p4.u;
    }
    int mm = lane & 15, quad = lane >> 4;
    short8 a[4];
#pragma unroll
    for (int ks = 0; ks < 4; ks++)
        a[ks] = *(const short8*)&T[mm * MPAD + ks * 32 + quad * 8];
    const short8* B1 = (const short8*)W1p + lane;
    f32x4 acc[8];
#pragma unroll
    for (int t = 0; t < 8; t++) acc[t] = (f32x4){0.f, 0.f, 0.f, 0.f};
#pragma unroll
    for (int ks = 0; ks < 4; ks++)
#pragma unroll
        for (int t = 0; t < 8; t++)
            acc[t] = __builtin_amdgcn_mfma_f32_16x16x32_f16(
                a[ks], B1[(t * 4 + ks) * 64], acc[t], 0, 0, 0);
#pragma unroll
    for (int t = 0; t < 8; t++) {
        int n = t * 16 + mm;
        float bias = b1[n];
#pragma unroll
        for (int r = 0; r < 4; r++)
            T[(quad * 4 + r) * MPAD + n] = __float2half(fmaxf(acc[t][r] + bias, 0.f));
    }
    short8 a2[4];
#pragma unroll
    for (int ks = 0; ks < 4; ks++)
        a2[ks] = *(const short8*)&T[mm * MPAD + ks * 32 + quad * 8];
    const short8* B2 = (const short8*)W2p + lane;
    f32x4 acc2[2];
#pragma unroll
    for (int t = 0; t < 2; t++) acc2[t] = (f32x4){0.f, 0.f, 0.f, 0.f};
#pragma unroll
    for (int ks = 0; ks < 4; ks++)
#pragma unroll
        for (int t = 0; t < 2; t++)
            acc2[t] = __builtin_amdgcn_mfma_f32_16x16x32_f16(
                a2[ks], B2[(t * 4 + ks) * 64], acc2[t], 0, 0, 0);
#pragma unroll
    for (int t = 0; t < 2; t++) {
        int n = t * 16 + mm;
        float bias = b2[n];
#pragma unroll
        for (int r = 0; r < 4; r++)
            out[(size_t)(rt * 16 + quad * 4 + r) * 32 + n] = acc2[t][r] + bias;
    }
}

// ---------------------------------------------------------------------------
extern "C" void kernel_launch(void* const* d_in, const int* in_sizes, int n_in,
                              void* d_out, int out_size, void* d_ws, size_t ws_size,
                              hipStream_t stream) {
    const float* x      = (const float*)d_in[0];
    const float* W_in   = (const float*)d_in[1];
    const float* b_in   = (const float*)d_in[2];
    const float* pre_W  = (const float*)d_in[3];
    const float* pre_b  = (const float*)d_in[4];
    const float* post_W = (const float*)d_in[5];
    const float* post_b = (const float*)d_in[6];
    const float* lin_W  = (const float*)d_in[7];
    const float* lin_b  = (const float*)d_in[8];
    const float* bn_g   = (const float*)d_in[9];
    const float* bn_b   = (const float*)d_in[10];
    const float* mlp_W1 = (const float*)d_in[11];
    const float* mlp_b1 = (const float*)d_in[12];
    const float* mlp_W2 = (const float*)d_in[13];
    const float* mlp_b2 = (const float*)d_in[14];
    const int*   edge   = (const int*)d_in[15];
    float* out = (float*)d_out;

    char* w = (char*)d_ws;
    const size_t plane = (size_t)NN * 128 * sizeof(float);       // 25.6 MB
    float* hbuf = (float*)w; w += plane;
    float* ybuf = (float*)w; w += plane;
    __half* Bpl = (__half*)w; w += plane;                        // both rels, f16
    int* fwd_nbr = (int*)w; w += (size_t)NN * DEG * sizeof(int);
    int* rev_nbr = (int*)w; w += (size_t)NN * DEG * sizeof(int);
    int* cnt     = (int*)w; w += (size_t)2 * NN * sizeof(int);
    float* Qw    = (float*)w; w += (size_t)2 * 128 * 128 * sizeof(float);
    float* bc    = (float*)w; w += 2 * 128 * sizeof(float);      // adjacent to Qw
    __half* Wcp  = (__half*)w; w += (size_t)2 * KSTEPS * 32 * 128 * sizeof(__half);
    __half* Winp = (__half*)w; w += (size_t)128 * 128 * sizeof(__half);
    __half* W1p  = (__half*)w; w += (size_t)128 * 128 * sizeof(__half);
    __half* W2p  = (__half*)w; w += (size_t)128 * 32 * sizeof(__half);
    float* bnsum  = (float*)w; w += 128 * sizeof(float);
    float* bnsum2 = (float*)w; w += 128 * sizeof(float);
    float* scale  = (float*)w; w += 128 * sizeof(float);
    float* shift  = (float*)w; w += 128 * sizeof(float);

    const int gWave = (RT_CNT + 3) / 4;  // 782 blocks (4 waves each)

    (void)hipMemsetAsync(cnt, 0, (size_t)2 * NN * sizeof(int), stream);
    (void)hipMemsetAsync(Qw, 0, (size_t)(2 * 128 * 128 + 2 * 128) * sizeof(float), stream);
    k_build_nbr<<<(EE + 255) / 256, 256, 0, stream>>>(edge, cnt, fwd_nbr, rev_nbr);
    k_wprep<<<16, 256, 0, stream>>>(post_W, pre_W, pre_b, post_b, lin_W, lin_b,
                                    Wcp, Qw, bc);
    k_pack_xt<<<16, 256, 0, stream>>>(Qw, Wcp);
    k_pack_b<<<8, 256, 0, stream>>>(W_in, 128, 128, Winp);
    k_pack_b<<<8, 256, 0, stream>>>(mlp_W1, 128, 128, W1p);
    k_pack_b<<<2, 256, 0, stream>>>(mlp_W2, 128, 32, W2p);

    // h = relu(x @ W_in + b_in)  (MFMA)
    k_in_mfma<<<gWave, 256, 0, stream>>>(x, Winp, b_in, hbuf);

    for (int l = 0; l < 2; l++) {
        if (l == 0)
            k_preB<0><<<RT_CNT, 256, 0, stream>>>(hbuf, nullptr, nullptr, nullptr,
                                                  pre_W, 0, Bpl);
        else  // fused: h1 = relu(bn(y0)) -> hbuf, plus B planes
            k_preB<1><<<RT_CNT, 256, 0, stream>>>(ybuf, scale, shift, hbuf,
                                                  pre_W, 1, Bpl);
        (void)hipMemsetAsync(bnsum, 0, 2 * 128 * sizeof(float), stream);
        k_agg_gemm<<<RT_CNT, 256, 0, stream>>>(
            hbuf, Bpl, fwd_nbr, rev_nbr, Wcp + (size_t)l * KSTEPS * 32 * 128,
            bc + l * 128, ybuf, bnsum, bnsum2);
        k_bn_final<<<1, 128, 0, stream>>>(bnsum, bnsum2, bn_g, bn_b, l, scale, shift);
    }

    // out = relu(bn_relu(y) @ mlp_W1 + b1) @ mlp_W2 + b2   (fused, MFMA)
    k_mlp_mfma<<<gWave, 256, 0, stream>>>(ybuf, scale, shift, W1p, mlp_b1,
                                          W2p, mlp_b2, out);
}